// Round 14
// baseline (608.467 us; speedup 1.0000x reference)
//
#include <hip/hip_runtime.h>
#include <math.h>

#define DIM    768
#define NTOK   2048
#define NSEQ   512
#define NBATCH 4
#define NHEADS 12
#define HD     64
#define QKVC   2304
#define MHEADS 8
#define MHD    96
#define NEXP   8
#define EDIM   3072
#define DD     (DIM*DIM)

typedef unsigned short u16;
typedef __attribute__((ext_vector_type(8))) short short8;
typedef __attribute__((ext_vector_type(4))) float f32x4;

struct L3 { long a, b, c; };
struct I3 { int a, b, c; };
struct CJ { const float4* s[6]; ushort4* d[6]; int n4[6]; };

__device__ __forceinline__ float gelu_exact(float v){
    return 0.5f * v * (1.f + erff(v * 0.70710678118654752f));
}
__device__ __forceinline__ u16 f2bf(float f){
    unsigned int u = __builtin_bit_cast(unsigned int, f);
    unsigned int r = (u + 0x7FFFu + ((u >> 16) & 1u)) >> 16;
    return (u16)r;
}
__device__ __forceinline__ float bf2f(u16 b){
    unsigned int u = ((unsigned int)b) << 16;
    return __builtin_bit_cast(float, u);
}
__device__ __forceinline__ float fast_tanh(float s){
    return 1.f - 2.f/(__expf(2.f*s) + 1.f);
}
// async global->LDS, 16B per lane; LDS dest linear (wave-uniform base + lane*16)
__device__ __forceinline__ void gll16(const u16* g, u16* l){
    __builtin_amdgcn_global_load_lds((const __attribute__((address_space(1))) void*)g,
                                     (__attribute__((address_space(3))) void*)l, 16, 0, 0);
}

// ================= MFMA bf16 GEMM core =================
// Per-wave tile (16*FR)^2; block tile (WM*16*FR)x(WN*16*FR); BK=64; WM*WN waves.
// DB=1: double-buffered LDS (stage t+1 issued before compute t, ONE barrier/k-step).
// DB=0: single buffer, 2 barriers/k-step.
// R9: counted-vmcnt + extra barrier REGRESSED. R10: 128^2 FR=4 regresses latency-bound experts.
// R12/R13: FR=1 (32x32 tile, 16KB LDS) wins for occupancy-starved stubby GEMMs (chain + down-proj).
// R14: same FR=1 treatment for expert up-proj.
// XOR-swizzled LDS via pre-swizzled global SOURCE + linear global_load_lds dest (m201 rule).
template<int WM,int WN,int FR,int DB>
__device__ __forceinline__ void mgemm_core(
    const u16* __restrict__ Xb, int ldx, int rowBase, int rowLim,
    const u16* __restrict__ Wb, int ldw, int colBase, int colLim, int K,
    const float* __restrict__ bias,
    const float* __restrict__ res, int ldres,
    float* __restrict__ Cf, u16* __restrict__ Cb, int ldc,
    float scale, int act)
{
    constexpr int TM = 16*FR;
    constexpr int RM = WM*TM, RN = WN*TM, NT = WM*WN*64;
    constexpr int IA = (RM*8)/NT, IB = (RN*8)/NT;
    constexpr int NB = DB ? 2 : 1;
    __shared__ u16 As[NB][RM*64];
    __shared__ u16 Bs[NB][RN*64];
    int tid = threadIdx.x;
    int lane = tid & 63, w = tid >> 6;
    int wm = (w / WN) * TM, wn = (w % WN) * TM;
    const f32x4 zf = {0.f, 0.f, 0.f, 0.f};
    f32x4 acc[FR][FR];
    #pragma unroll
    for (int i=0;i<FR;i++)
        #pragma unroll
        for (int j=0;j<FR;j++) acc[i][j] = zf;

    const bool fullA = (rowBase + RM <= rowLim);
    const bool fullB = (colBase + RN <= colLim);
    const int nt = (K + 63) >> 6;
    int lr = lane & 15, lk = lane >> 4;

    auto stage = [&](int buf, int k0){
        const bool kfull = (k0 + 64 <= K);
        if (fullA && kfull) {
            #pragma unroll
            for (int it = 0; it < IA; ++it) {
                int idx = it*NT + tid;
                int r = idx >> 3, c = idx & 7;
                gll16(&Xb[(size_t)(rowBase + r)*ldx + k0 + ((c ^ (r & 7)) << 3)], &As[buf][(size_t)idx*8]);
            }
        } else {
            #pragma unroll
            for (int it = 0; it < IA; ++it) {
                int idx = it*NT + tid;
                int r = idx >> 3, c = idx & 7;
                int gr = rowBase + r;
                uint4 v = {0u,0u,0u,0u};
                if (gr < rowLim && (k0 + c*8) < K) v = *(const uint4*)&Xb[(size_t)gr*ldx + k0 + c*8];
                *(uint4*)&As[buf][r*64 + ((c ^ (r & 7)) * 8)] = v;
            }
        }
        if (fullB && kfull) {
            #pragma unroll
            for (int it = 0; it < IB; ++it) {
                int idx = it*NT + tid;
                int r = idx >> 3, c = idx & 7;
                gll16(&Wb[(size_t)(colBase + r)*ldw + k0 + ((c ^ (r & 7)) << 3)], &Bs[buf][(size_t)idx*8]);
            }
        } else {
            #pragma unroll
            for (int it = 0; it < IB; ++it) {
                int idx = it*NT + tid;
                int r = idx >> 3, c = idx & 7;
                int gc = colBase + r;
                uint4 v = {0u,0u,0u,0u};
                if (gc < colLim && (k0 + c*8) < K) v = *(const uint4*)&Wb[(size_t)gc*ldw + k0 + c*8];
                *(uint4*)&Bs[buf][r*64 + ((c ^ (r & 7)) * 8)] = v;
            }
        }
    };
    auto compute = [&](const u16* Ac, const u16* Bc){
        #pragma unroll
        for (int ks = 0; ks < 2; ++ks) {
            short8 af[FR], bfr[FR];
            #pragma unroll
            for (int mi=0; mi<FR; mi++){
                int row = wm + mi*16 + lr;
                int cidx = (ks*4 + lk) ^ (row & 7);
                af[mi] = *(const short8*)&Ac[row*64 + cidx*8];
            }
            #pragma unroll
            for (int ni=0; ni<FR; ni++){
                int col = wn + ni*16 + lr;
                int cidx = (ks*4 + lk) ^ (col & 7);
                bfr[ni] = *(const short8*)&Bc[col*64 + cidx*8];
            }
            #pragma unroll
            for (int mi=0; mi<FR; mi++)
                #pragma unroll
                for (int ni=0; ni<FR; ni++)
                    acc[mi][ni] = __builtin_amdgcn_mfma_f32_16x16x32_bf16(af[mi], bfr[ni], acc[mi][ni], 0, 0, 0);
        }
    };

    if (DB) {
        stage(0, 0);
        __syncthreads();
        for (int t = 0; t < nt; ++t) {
            if (t + 1 < nt) stage((t+1)&1, (t+1)*64);
            compute(As[t&1], Bs[t&1]);
            __syncthreads();
        }
    } else {
        for (int t = 0; t < nt; ++t) {
            stage(0, t*64);
            __syncthreads();
            compute(As[0], Bs[0]);
            __syncthreads();
        }
    }
    // epilogue: D row = (lane>>4)*4 + reg, col = lane&15  [m89-verified]
    int lg = lane >> 4;
    #pragma unroll
    for (int mi=0; mi<FR; mi++){
        #pragma unroll
        for (int r=0; r<4; r++){
            int row = rowBase + wm + mi*16 + lg*4 + r;
            if (row >= rowLim) continue;
            #pragma unroll
            for (int ni=0; ni<FR; ni++){
                int col = colBase + wn + ni*16 + lr;
                if (col >= colLim) continue;
                float v = acc[mi][ni][r] * scale;
                if (bias) v += bias[col];
                if (act == 1) v = gelu_exact(v);
                if (Cb) Cb[(size_t)row*ldc + col] = f2bf(v);
                if (res) v += res[(size_t)row*ldres + col];
                if (Cf) Cf[(size_t)row*ldc + col] = v;
            }
        }
    }
}

template<int WM,int WN,int FR,int DB>
__global__ __launch_bounds__(WM*WN*64) void k_mgemm(
    const u16* __restrict__ X, int ldx, int M,
    const u16* __restrict__ W, int ldw, int N, int K,
    const float* __restrict__ bias, const float* __restrict__ res, int ldres,
    float* __restrict__ Cf, u16* __restrict__ Cb, int ldc, float scale, int act)
{
    constexpr int RM = WM*16*FR, RN = WN*16*FR;
    mgemm_core<WM,WN,FR,DB>(X, ldx, blockIdx.x*RM, M, W, ldw, blockIdx.y*RN, N, K,
                            bias, res, ldres, Cf, Cb, ldc, scale, act);
}

// batched-by-3 variant: z selects offsets into X/W/bias/C and M
template<int WM,int WN,int FR,int DB>
__global__ __launch_bounds__(WM*WN*64) void k_mgemm_b3(
    const u16* __restrict__ X, L3 xo, int ldx, I3 Mv,
    const u16* __restrict__ W, L3 wo, int ldw, int N, int K,
    const float* __restrict__ bias, L3 bo,
    u16* __restrict__ Cb, L3 co, int ldc, float scale, int act)
{
    constexpr int RM = WM*16*FR, RN = WN*16*FR;
    int z = blockIdx.z;
    int M    = (z==0) ? Mv.a : (z==1) ? Mv.b : Mv.c;
    long xof = (z==0) ? xo.a : (z==1) ? xo.b : xo.c;
    long wof = (z==0) ? wo.a : (z==1) ? wo.b : wo.c;
    long bof = (z==0) ? bo.a : (z==1) ? bo.b : bo.c;
    long cof = (z==0) ? co.a : (z==1) ? co.b : co.c;
    if ((int)blockIdx.x * RM >= M) return;
    mgemm_core<WM,WN,FR,DB>(X + xof, ldx, blockIdx.x*RM, M, W + wof, ldw, blockIdx.y*RN, N, K,
                            bias ? bias + bof : nullptr, nullptr, 0, nullptr, Cb + cof, ldc, scale, act);
}

template<int WM,int WN,int FR,int DB>
__global__ __launch_bounds__(WM*WN*64) void k_mgemm_expert(
    const u16* __restrict__ X, int ldx,
    const u16* __restrict__ Wb, int ldw, long wStride,
    const float* __restrict__ biasB, int biasStride,
    const int* __restrict__ prefix, const int* __restrict__ cnt,
    float* __restrict__ Cf, u16* __restrict__ Cb, int ldc, int N, int K, int act)
{
    constexpr int RM = WM*16*FR, RN = WN*16*FR;
    int e = blockIdx.z;
    int n = cnt[e];
    if ((int)blockIdx.x * RM >= n) return;
    mgemm_core<WM,WN,FR,DB>(X, ldx, prefix[e] + blockIdx.x*RM, prefix[e] + n,
                            Wb + (size_t)e*wStride, ldw, blockIdx.y*RN, N, K,
                            biasB + (size_t)e*biasStride, nullptr, 0, Cf, Cb, ldc, 1.f, act);
}

// scores[b,h,n,m] = 0.125 * q_n . k_m  (bf16 out)
template<int WM,int WN,int FR,int DB>
__global__ __launch_bounds__(WM*WN*64) void k_mgemm_qk(const u16* __restrict__ qkv, u16* __restrict__ attn)
{
    constexpr int RM = WM*16*FR, RN = WN*16*FR;
    int z = blockIdx.z, b = z / NHEADS, h = z % NHEADS;
    const u16* X = qkv + (size_t)b*NSEQ*QKVC + h*HD;          // q
    const u16* W = qkv + (size_t)b*NSEQ*QKVC + DIM + h*HD;    // k
    u16* C = attn + (size_t)z*NSEQ*NSEQ;
    mgemm_core<WM,WN,FR,DB>(X, QKVC, blockIdx.x*RM, NSEQ, W, QKVC, blockIdx.y*RN, NSEQ, HD,
                            nullptr, nullptr, 0, nullptr, C, NSEQ, 0.125f, 0);
}

// o[b,n,h*64+d] = sum_m P[b,h,n,m] * V[b,m,h*64+d]; Vt[b][d][m] supplies W
template<int WM,int WN,int FR,int DB>
__global__ __launch_bounds__(WM*WN*64) void k_mgemm_pv(const u16* __restrict__ P, const u16* __restrict__ Vt, u16* __restrict__ o)
{
    constexpr int RM = WM*16*FR, RN = WN*16*FR;
    int z = blockIdx.z, b = z / NHEADS, h = z % NHEADS;
    const u16* X = P + (size_t)z*NSEQ*NSEQ;
    const u16* W = Vt + ((size_t)b*DIM + h*HD)*NSEQ;
    u16* C = o + (size_t)b*NSEQ*DIM + h*HD;
    mgemm_core<WM,WN,FR,DB>(X, NSEQ, blockIdx.x*RM, NSEQ, W, NSEQ, blockIdx.y*RN, HD, NSEQ,
                            nullptr, nullptr, 0, nullptr, C, DIM, 1.f, 0);
}

// ===== Gt build: Gt[l][j][h*M+m] = sum_d Wc[l][j][h*96+d] * V[l][m][h*96+d] =====
template<int WM,int WN,int FR,int DB>
__global__ __launch_bounds__(WM*WN*64) void k_gt(
    const u16* __restrict__ Wc, const u16* __restrict__ kvL, long kvStride,
    u16* __restrict__ Gt, long gtStride, I3 Mv)
{
    constexpr int RM = WM*16*FR, RN = WN*16*FR;
    int z = blockIdx.z, l = z >> 3, h = z & 7;
    int M = (l==0) ? Mv.a : (l==1) ? Mv.b : Mv.c;
    if ((int)blockIdx.y * RN >= M) return;
    mgemm_core<WM,WN,FR,DB>(Wc + (size_t)l*DD + h*MHD, DIM, blockIdx.x*RM, DIM,
                            kvL + (size_t)l*kvStride + DIM + h*MHD, 2*DIM, blockIdx.y*RN, M, MHD,
                            nullptr, nullptr, 0, nullptr,
                            Gt + (size_t)l*gtStride + (size_t)h*M, 8*M, 1.f, 0);
}

// ===== fused mem-MHA scores + row softmax: block = 64 q-rows x full M (<=256), 4 waves =====
// writes P[n][h*M+m] (token-major) so the PV+proj GEMM consumes it as one (2048 x 8M) operand
__global__ __launch_bounds__(256) void k_memqk_soft(
    const u16* __restrict__ q, const u16* __restrict__ kv, int ldk,
    u16* __restrict__ P, int M, float scale)
{
    constexpr int RM = 64, RN = 256, NT = 256, K = MHD;
    __shared__ u16 As[RM*64];
    __shared__ u16 Bs[RN*64];
    __shared__ float red0[RM][4];
    __shared__ float red1[RM][4];
    int h = blockIdx.y;
    int rowBase = blockIdx.x * RM;
    const u16* Xb = q + h*MHD;     // ldx = DIM
    const u16* Wb = kv + h*MHD;    // ldw = ldk
    int tid = threadIdx.x, lane = tid & 63, w = tid >> 6;
    int wn = w * 64;
    int lr = lane & 15, lk = lane >> 4;
    const f32x4 zf = {0.f,0.f,0.f,0.f};
    f32x4 acc[4][4];
    #pragma unroll
    for (int i=0;i<4;i++)
        #pragma unroll
        for (int j=0;j<4;j++) acc[i][j] = zf;

    for (int k0 = 0; k0 < K; k0 += 64) {
        const bool kfull = (k0 + 64 <= K);
        if (kfull) {
            #pragma unroll
            for (int it = 0; it < 2; ++it) {
                int idx = it*NT + tid;
                int r = idx >> 3, c = idx & 7;
                gll16(&Xb[(size_t)(rowBase + r)*DIM + k0 + ((c ^ (r & 7)) << 3)], &As[(size_t)idx*8]);
            }
        } else {
            #pragma unroll
            for (int it = 0; it < 2; ++it) {
                int idx = it*NT + tid;
                int r = idx >> 3, c = idx & 7;
                uint4 v = {0u,0u,0u,0u};
                if ((k0 + c*8) < K) v = *(const uint4*)&Xb[(size_t)(rowBase + r)*DIM + k0 + c*8];
                *(uint4*)&As[r*64 + ((c ^ (r & 7)) * 8)] = v;
            }
        }
        #pragma unroll
        for (int it = 0; it < 8; ++it) {
            int idx = it*NT + tid;
            int r = idx >> 3, c = idx & 7;
            uint4 v = {0u,0u,0u,0u};
            if (r < M && (k0 + c*8) < K) v = *(const uint4*)&Wb[(size_t)r*ldk + k0 + c*8];
            *(uint4*)&Bs[r*64 + ((c ^ (r & 7)) * 8)] = v;
        }
        __syncthreads();
        #pragma unroll
        for (int ks = 0; ks < 2; ++ks) {
            short8 af[4], bfr[4];
            #pragma unroll
            for (int mi=0; mi<4; mi++){
                int row = mi*16 + lr;
                int cidx = (ks*4 + lk) ^ (row & 7);
                af[mi] = *(const short8*)&As[row*64 + cidx*8];
            }
            #pragma unroll
            for (int ni=0; ni<4; ni++){
                int col = wn + ni*16 + lr;
                int cidx = (ks*4 + lk) ^ (col & 7);
                bfr[ni] = *(const short8*)&Bs[col*64 + cidx*8];
            }
            #pragma unroll
            for (int mi=0; mi<4; mi++)
                #pragma unroll
                for (int ni=0; ni<4; ni++)
                    acc[mi][ni] = __builtin_amdgcn_mfma_f32_16x16x32_bf16(af[mi], bfr[ni], acc[mi][ni], 0, 0, 0);
        }
        __syncthreads();
    }
    int lg = lane >> 4;
    float sc[4][4][4];
    float rmax[4][4];
    #pragma unroll
    for (int mi=0; mi<4; mi++){
        #pragma unroll
        for (int r=0; r<4; r++){
            float m = -1e30f;
            #pragma unroll
            for (int ni=0; ni<4; ni++){
                int col = wn + ni*16 + lr;
                float v = (col < M) ? acc[mi][ni][r]*scale : -1e30f;
                sc[mi][r][ni] = v;
                m = fmaxf(m, v);
            }
            m = fmaxf(m, __shfl_xor(m, 1));
            m = fmaxf(m, __shfl_xor(m, 2));
            m = fmaxf(m, __shfl_xor(m, 4));
            m = fmaxf(m, __shfl_xor(m, 8));
            rmax[mi][r] = m;
        }
    }
    if (lr == 0){
        #pragma unroll
        for (int mi=0; mi<4; mi++)
            #pragma unroll
            for (int r=0; r<4; r++) red0[mi*16 + lg*4 + r][w] = rmax[mi][r];
    }
    __syncthreads();
    float gmax[4][4], rsum[4][4];
    #pragma unroll
    for (int mi=0; mi<4; mi++){
        #pragma unroll
        for (int r=0; r<4; r++){
            int row = mi*16 + lg*4 + r;
            float g = fmaxf(fmaxf(red0[row][0], red0[row][1]), fmaxf(red0[row][2], red0[row][3]));
            gmax[mi][r] = g;
            float s = 0.f;
            #pragma unroll
            for (int ni=0; ni<4; ni++){
                int col = wn + ni*16 + lr;
                if (col < M) s += __expf(sc[mi][r][ni] - g);
            }
            s += __shfl_xor(s, 1);
            s += __shfl_xor(s, 2);
            s += __shfl_xor(s, 4);
            s += __shfl_xor(s, 8);
            rsum[mi][r] = s;
        }
    }
    if (lr == 0){
        #pragma unroll
        for (int mi=0; mi<4; mi++)
            #pragma unroll
            for (int r=0; r<4; r++) red1[mi*16 + lg*4 + r][w] = rsum[mi][r];
    }
    __syncthreads();
    #pragma unroll
    for (int mi=0; mi<4; mi++){
        #pragma unroll
        for (int r=0; r<4; r++){
            int row = mi*16 + lg*4 + r;
            float tot = red1[row][0] + red1[row][1] + red1[row][2] + red1[row][3];
            float inv = 1.f / tot;
            #pragma unroll
            for (int ni=0; ni<4; ni++){
                int col = wn + ni*16 + lr;
                if (col < M)
                    P[(((size_t)(rowBase + row))*MHEADS + h)*M + col] = f2bf(__expf(sc[mi][r][ni] - gmax[mi][r]) * inv);
            }
        }
    }
}

// batched outw transpose: wT3[z][c][r] = outw[z][r][c]
__global__ __launch_bounds__(256) void k_transw_b(const u16* __restrict__ src, u16* __restrict__ dst)
{
    int z = blockIdx.y;
    int idx = blockIdx.x*256 + threadIdx.x;
    int r = idx / DIM, c = idx % DIM;
    dst[(size_t)z*DD + (size_t)c*DIM + r] = src[(size_t)z*DD + (size_t)r*DIM + c];
}

// ================= PHM weight materialization, 4-wide (Si divisible by 4) =================
__global__ __launch_bounds__(256) void k_phm4(
    const float* __restrict__ A, const float* __restrict__ S, void* __restrict__ W,
    int So, int Si, int inF, long Astride, long Sstride, long Wstride, int obf)
{
    int e = blockIdx.y;
    const float* Ae = A + (size_t)e*Astride;
    const float* Se = S + (size_t)e*Sstride;
    size_t idx = (size_t)blockIdx.x*256 + threadIdx.x;
    int inF4 = inF >> 2;
    size_t total = (size_t)(So*4) * inF4;
    if (idx >= total) return;
    int in4 = (int)(idx % inF4);
    int o   = (int)(idx / inF4);
    int a = o / So, c = o % So;
    int in0 = in4 * 4;
    int b = in0 / Si, d = in0 % Si;
    float4 acc = {0.f,0.f,0.f,0.f};
    #pragma unroll
    for (int i=0;i<4;i++){
        float av = Ae[i*16 + a*4 + b];
        float4 sv = *(const float4*)&Se[((size_t)i*So + c)*Si + d];
        acc.x = fmaf(av, sv.x, acc.x);
        acc.y = fmaf(av, sv.y, acc.y);
        acc.z = fmaf(av, sv.z, acc.z);
        acc.w = fmaf(av, sv.w, acc.w);
    }
    size_t oidx = (size_t)o*inF + in0;
    if (obf){
        ushort4 r; r.x=f2bf(acc.x); r.y=f2bf(acc.y); r.z=f2bf(acc.z); r.w=f2bf(acc.w);
        *(ushort4*)&((u16*)W)[(size_t)e*Wstride + oidx] = r;
    } else {
        *(float4*)&((float*)W)[(size_t)e*Wstride + oidx] = acc;
    }
}

// ================= fp32 -> bf16 converts =================
__global__ __launch_bounds__(256) void k_cvt4(const float4* __restrict__ s, ushort4* __restrict__ d, int n4)
{
    for (int i = blockIdx.x*256 + threadIdx.x; i < n4; i += gridDim.x*256){
        float4 v = s[i];
        ushort4 o; o.x = f2bf(v.x); o.y = f2bf(v.y); o.z = f2bf(v.z); o.w = f2bf(v.w);
        d[i] = o;
    }
}
__global__ __launch_bounds__(256) void k_cvt_multi(CJ J)
{
    int z = blockIdx.y;
    const float4* s = J.s[z]; ushort4* d = J.d[z]; int n4 = J.n4[z];
    for (int i = blockIdx.x*256 + threadIdx.x; i < n4; i += gridDim.x*256){
        float4 v = s[i];
        ushort4 o; o.x = f2bf(v.x); o.y = f2bf(v.y); o.z = f2bf(v.z); o.w = f2bf(v.w);
        d[i] = o;
    }
}

// bc[l][i] = dot(pw[l][i][:], outb[l][:]) + pb[l][i]
__global__ __launch_bounds__(256) void k_bc(const float* __restrict__ pw, const float* __restrict__ outb,
                                            const float* __restrict__ pb, float* __restrict__ bc)
{
    int l = blockIdx.y;
    int i = blockIdx.x*4 + (threadIdx.x >> 6);
    int lane = threadIdx.x & 63;
    const float* pr = pw + ((size_t)l*DIM + i)*DIM;
    const float* ob = outb + (size_t)l*DIM;
    float s = 0.f;
    for (int j = lane; j < DIM; j += 64) s = fmaf(pr[j], ob[j], s);
    for (int off=32; off; off>>=1) s += __shfl_xor(s, off);
    if (lane == 0) bc[(size_t)l*DIM + i] = s + pb[(size_t)l*DIM + i];
}

// ================= LayerNorm (row=768), dual output =================
__global__ __launch_bounds__(256) void k_ln(const float* __restrict__ x, const float* __restrict__ g,
                                            const float* __restrict__ b,
                                            float* __restrict__ yf, u16* __restrict__ yb)
{
    int row = blockIdx.x, tid = threadIdx.x;
    const float* xr = x + (size_t)row * DIM;
    float v0 = xr[tid], v1 = xr[tid+256], v2 = xr[tid+512];
    float s = v0+v1+v2;
    float ss = v0*v0 + v1*v1 + v2*v2;
    for (int off=32; off; off>>=1){ s += __shfl_xor(s,off); ss += __shfl_xor(ss,off); }
    __shared__ float sa[4], sb[4];
    int wid = tid >> 6;
    if ((tid & 63) == 0){ sa[wid]=s; sb[wid]=ss; }
    __syncthreads();
    s  = sa[0]+sa[1]+sa[2]+sa[3];
    ss = sb[0]+sb[1]+sb[2]+sb[3];
    float mean = s * (1.f/DIM);
    float var  = ss * (1.f/DIM) - mean*mean;
    float rstd = rsqrtf(var + 1e-5f);
    float o0 = (v0-mean)*rstd*g[tid]     + b[tid];
    float o1 = (v1-mean)*rstd*g[tid+256] + b[tid+256];
    float o2 = (v2-mean)*rstd*g[tid+512] + b[tid+512];
    if (yf){ float* yr = yf + (size_t)row*DIM; yr[tid]=o0; yr[tid+256]=o1; yr[tid+512]=o2; }
    if (yb){ u16* yr = yb + (size_t)row*DIM; yr[tid]=f2bf(o0); yr[tid+256]=f2bf(o1); yr[tid+512]=f2bf(o2); }
}

// ===== fused sup/ent mix + tanh + softmax (bf16 scores in, uint4 loads): block per (b,n) =====
__global__ __launch_bounds__(256) void k_supsoft(
    const u16* __restrict__ attn, u16* __restrict__ P,
    const float* __restrict__ wsup, const float* __restrict__ went)
{
    __shared__ float S[NHEADS][NSEQ];
    __shared__ float ws[144], we[144];
    int bn = blockIdx.x;
    int b = bn >> 9, n = bn & 511;
    int tid = threadIdx.x;
    if (tid < 144){ ws[tid] = wsup[tid]; we[tid] = went[tid]; }
    size_t base = ((size_t)b*NHEADS*NSEQ + n)*NSEQ;
    #pragma unroll
    for (int it=0; it<3; ++it){
        int idx = it*256 + tid;
        int j = idx >> 6, m8 = (idx & 63) * 8;
        uint4 v = *(const uint4*)&attn[base + (size_t)j*NSEQ*NSEQ + m8];
        S[j][m8+0] = bf2f((u16)(v.x & 0xFFFFu)); S[j][m8+1] = bf2f((u16)(v.x >> 16));
        S[j][m8+2] = bf2f((u16)(v.y & 0xFFFFu)); S[j][m8+3] = bf2f((u16)(v.y >> 16));
        S[j][m8+4] = bf2f((u16)(v.z & 0xFFFFu)); S[j][m8+5] = bf2f((u16)(v.z >> 16));
        S[j][m8+6] = bf2f((u16)(v.w & 0xFFFFu)); S[j][m8+7] = bf2f((u16)(v.w >> 16));
    }
    __syncthreads();
    #pragma unroll
    for (int half=0; half<2; ++half){
        int m = tid + half*256;
        float av[12], sup[12];
        #pragma unroll
        for (int j=0;j<12;j++) av[j] = S[j][m];
        #pragma unroll
        for (int i=0;i<12;i++){
            float s = 0.f;
            #pragma unroll
            for (int j=0;j<12;j++) s = fmaf(ws[i*12+j], av[j], s);
            sup[i] = s;
        }
        #pragma unroll
        for (int i=0;i<12;i++){
            float s = sup[i];
            #pragma unroll
            for (int j=0;j<12;j++) s = fmaf(we[i*12+j], sup[j], s);
            av[i] = fast_tanh(s);
        }
        #pragma unroll
        for (int i=0;i<12;i++) S[i][m] = av[i];
    }
    __syncthreads();
    int lane = tid & 63, wv = tid >> 6;
    #pragma unroll
    for (int jj=0; jj<3; ++jj){
        int j = wv*3 + jj;
        float v[8], mx = -1e30f;
        #pragma unroll
        for (int k=0;k<8;k++){ v[k] = S[j][lane + 64*k]; mx = fmaxf(mx, v[k]); }
        for (int off=32; off; off>>=1) mx = fmaxf(mx, __shfl_xor(mx, off));
        float sum = 0.f;
        #pragma unroll
        for (int k=0;k<8;k++){ v[k] = __expf(v[k]-mx); sum += v[k]; }
        for (int off=32; off; off>>=1) sum += __shfl_xor(sum, off);
        float inv = 1.f/sum;
        #pragma unroll
        for (int k=0;k<8;k++) P[base + (size_t)j*NSEQ*NSEQ + lane + 64*k] = f2bf(v[k]*inv);
    }
}

// ================= V transpose (main attn): Vt[b][d][m] = qkv_bf[b][m][1536+d] =================
__global__ __launch_bounds__(256) void k_transv(const u16* __restrict__ qkv, u16* __restrict__ Vt)
{
    __shared__ u16 L[64][65];
    int mt = blockIdx.x*64, dt = blockIdx.y*64, b = blockIdx.z;
    int tid = threadIdx.x;
    #pragma unroll
    for (int it=0; it<16; ++it){
        int idx = it*256 + tid;
        int mm = idx >> 6, dd = idx & 63;
        L[mm][dd] = qkv[((size_t)b*NSEQ + mt + mm)*QKVC + 1536 + dt + dd];
    }
    __syncthreads();
    #pragma unroll
    for (int it=0; it<16; ++it){
        int idx = it*256 + tid;
        int dd = idx >> 6, mm = idx & 63;
        Vt[((size_t)b*DIM + dt + dd)*NSEQ + mt + mm] = L[mm][dd];
    }
}

// ================= MoE routing (bf16 input) =================
__global__ __launch_bounds__(256) void k_route(
    const u16* __restrict__ ln2, const float* __restrict__ Wr,
    const float* __restrict__ rb, const float* __restrict__ dr,
    const int* __restrict__ did, int* __restrict__ topi, float* __restrict__ topw, int* __restrict__ cnt)
{
    int t = blockIdx.x, tid = threadIdx.x;
    const u16* xr = ln2 + (size_t)t*DIM;
    float a[8] = {};
    #pragma unroll
    for (int ii=0; ii<3; ii++){
        int i = tid + ii*256;
        float xv = bf2f(xr[i]);
        #pragma unroll
        for (int e=0;e<8;e++) a[e] = fmaf(xv, Wr[e*DIM + i], a[e]);
    }
    #pragma unroll
    for (int e=0;e<8;e++)
        for (int off=32; off; off>>=1) a[e] += __shfl_xor(a[e], off);
    __shared__ float sred[4][8];
    int wid = tid >> 6;
    if ((tid & 63) == 0){
        #pragma unroll
        for (int e=0;e<8;e++) sred[wid][e] = a[e];
    }
    __syncthreads();
    if (tid == 0){
        int d = did[0];
        float lg[8];
        #pragma unroll
        for (int e=0;e<8;e++) lg[e] = sred[0][e]+sred[1][e]+sred[2][e]+sred[3][e] + rb[e] + dr[d*8+e];
        int i1 = 0; float v1 = lg[0];
        #pragma unroll
        for (int e=1;e<8;e++) if (lg[e] > v1){ v1 = lg[e]; i1 = e; }
        int i2 = -1; float v2 = -1e30f;
        #pragma unroll
        for (int e=0;e<8;e++) if (e != i1 && lg[e] > v2){ v2 = lg[e]; i2 = e; }
        float e2 = __expf(v2 - v1);
        float inv = 1.f / (1.f + e2);
        topi[2*t] = i1; topi[2*t+1] = i2;
        topw[2*t] = inv; topw[2*t+1] = e2 * inv;
        atomicAdd(&cnt[i1], 1); atomicAdd(&cnt[i2], 1);
    }
}

__global__ void k_zero(int* p, int n){ int i = threadIdx.x; if (i < n) p[i] = 0; }

__global__ void k_prefix(const int* __restrict__ cnt, int* __restrict__ prefix){
    if (threadIdx.x == 0){ int s=0; for (int e=0;e<8;e++){ prefix[e]=s; s+=cnt[e]; } }
}

__global__ __launch_bounds__(256) void k_assign(
    const int* __restrict__ topi, const int* __restrict__ prefix,
    int* __restrict__ cnt2, int* __restrict__ rowof, int* __restrict__ tokof)
{
    int t = blockIdx.x*256 + threadIdx.x;
    if (t >= NTOK) return;
    #pragma unroll
    for (int k=0;k<2;k++){
        int e = topi[2*t+k];
        int slot = atomicAdd(&cnt2[e], 1);
        int row = prefix[e] + slot;
        rowof[2*t+k] = row;
        tokof[row] = t;
    }
}

// 16B-vectorized gather
__global__ __launch_bounds__(256) void k_gather(const u16* __restrict__ src, const int* __restrict__ tokof, u16* __restrict__ dst)
{
    int i = blockIdx.x*256 + threadIdx.x;
    int row = i / 96, c = (i % 96) * 8;
    *(uint4*)&dst[(size_t)row*DIM + c] = *(const uint4*)&src[(size_t)tokof[row]*DIM + c];
}

__global__ __launch_bounds__(256) void k_combine(
    const float* __restrict__ att, const float* __restrict__ outg,
    const int* __restrict__ rowof, const float* __restrict__ topw,
    float* __restrict__ eo, u16* __restrict__ eob)
{
    size_t i = (size_t)blockIdx.x*256 + threadIdx.x;
    int t = (int)(i / DIM), c = (int)(i % DIM);
    int r0 = rowof[2*t], r1 = rowof[2*t+1];
    float v = att[i] + topw[2*t]*outg[(size_t)r0*DIM+c] + topw[2*t+1]*outg[(size_t)r1*DIM+c];
    eo[i] = v;
    eob[i] = f2bf(v);
}

// ================= host =================
extern "C" void kernel_launch(void* const* d_in, const int* in_sizes, int n_in,
                              void* d_out, int out_size, void* d_ws, size_t ws_size,
                              hipStream_t stream)
{
    const float* x     = (const float*)d_in[0];
    const float* ln1g  = (const float*)d_in[1];
    const float* ln1b  = (const float*)d_in[2];
    const float* ln2g  = (const float*)d_in[3];
    const float* ln2b  = (const float*)d_in[4];
    const float* ln3g  = (const float*)d_in[5];
    const float* ln3b  = (const float*)d_in[6];
    const float* qkvA  = (const float*)d_in[7];
    const float* qkvS  = (const float*)d_in[8];
    const float* qkvb  = (const float*)d_in[9];
    const float* projA = (const float*)d_in[10];
    const float* projS = (const float*)d_in[11];
    const float* projb = (const float*)d_in[12];
    const float* wsup  = (const float*)d_in[13];
    const float* went  = (const float*)d_in[14];
    const float* rA    = (const float*)d_in[15];
    const float* rS    = (const float*)d_in[16];
    const float* rb    = (const float*)d_in[17];
    const float* dr    = (const float*)d_in[18];
    const float* eA    = (const float*)d_in[19];
    const float* eS    = (const float*)d_in[20];
    const float* eb    = (const float*)d_in[21];
    const float* ndw   = (const float*)d_in[22];
    const float* ndb   = (const float*)d_in[23];
    const float* mem0  = (const float*)d_in[24];
    const float* mem1  = (const float*)d_in[25];
    const float* mem2  = (const float*)d_in[26];
    const float* inw   = (const float*)d_in[27];
    const float* inb   = (const float*)d_in[28];
    const float* outw  = (const float*)d_in[29];
    const float* outb  = (const float*)d_in[30];
    const float* pw    = (const float*)d_in[31];
    const float* pb    = (const float*)d_in[32];
    const int*   did   = (const int*)d_in[33];

    float* f = (float*)d_ws;
    size_t off = 0;
    auto alloc = [&](size_t n){ float* p = f + off; off += (n + 3) & ~(size_t)3; return p; };
    auto allocb = [&](size_t n){ return (u16*)alloc((n + 1) / 2); };

    // fp32 buffers
    float* attnd  = alloc((size_t)NTOK*DIM);
    float* eo     = alloc((size_t)NTOK*DIM);
    float* accum  = alloc((size_t)NTOK*DIM);
    float* attnb  = alloc((size_t)48*NSEQ*NSEQ);   // u16 scores; hosts outg + ndw_bf
    float* Wrout  = alloc((size_t)NEXP*DIM);
    float* topw   = alloc((size_t)2*NTOK);
    float* bcb    = alloc((size_t)3*DIM);
    int* ip = (int*)alloc((size_t)6*NTOK + 64);
    int* topi   = ip;            ip += 2*NTOK;
    int* rowof  = ip;            ip += 2*NTOK;
    int* tokof  = ip;            ip += 2*NTOK;
    int* cnt    = ip;            ip += 8;
    int* cnt2   = ip;            ip += 8;
    int* prefix = ip;            ip += 8;

    // aliases inside attnb (scores dead after supsoft)
    u16*   scores = (u16*)attnb;                         // 48*512*512 u16
    float* outg   = attnb;                               // 4096x768 fp32 (MoE)
    u16*   ndw_bf = (u16*)(attnb + (size_t)3146240);     // 18.87M u16 (MoE)

    // bf16 buffers
    u16* Wqkv_bf  = allocb((size_t)QKVC*DIM);
    u16* Wproj_bf = allocb((size_t)DD);
    u16* Wexp_bf  = allocb((size_t)NEXP*EDIM*DIM);
    u16* inw_bf   = allocb((size_t)3*QKVC*DIM);
    u16* outw_bf  = allocb((size_t)3*DD);
    u16* pw_bf    = allocb((size_t)3*DD);
    u16* Wc_bf    = allocb((size_t)3*DD);
    u16* wT3_bf   = allocb((size_t)3*DD);
    u16* mem_bf   = allocb((size_t)448*DIM);
    u16* qkv_bf   = allocb((size_t)NTOK*QKVC);     // hosts Xg_bf later
    u16* Vt_bf    = allocb((size_t)NBATCH*DIM*NSEQ);
    u16* P_bf     = allocb((size_t)48*NSEQ*NSEQ);  // also hidden_bf, later Pm_bf
    u16* lnx_bf   = allocb((size_t)NTOK*DIM);
    u16* o_bf     = allocb((size_t)NTOK*DIM);      // attn out; later qm_bf
    u16* inx_bf   = allocb((size_t)NTOK*DIM);
    u16* kvL_bf   = allocb((size_t)3*256*2*DIM);   // [3][256][1536] fused K|V per level
    u16* Gt_bf    = allocb((size_t)3*768*2048);    // [3][768][8*M_l] fused PV+proj weights
    u16* Xg_bf    = qkv_bf;
    u16* hidden_bf= P_bf;
    u16* Pm_bf    = P_bf;
    u16* qm_bf    = o_bf;

    float* outf = (float*)d_out;
    dim3 T256(256), T64(64);
    I3 Ms3 = {64, 128, 256};

    k_zero<<<1, 32, 0, stream>>>(cnt, 16);
    k_ln<<<NTOK, T256, 0, stream>>>(x, ln1g, ln1b, nullptr, lnx_bf);
    // PHM weight builds (bf16 except router), 4-wide
    k_phm4<<<dim3(1728,1), T256, 0, stream>>>(qkvA, qkvS, Wqkv_bf, 576, 192, DIM, 0,0,0, 1);
    k_phm4<<<dim3(576,1),  T256, 0, stream>>>(projA, projS, Wproj_bf, 192, 192, DIM, 0,0,0, 1);
    k_phm4<<<dim3(6,1),    T256, 0, stream>>>(rA, rS, Wrout, 2, 192, DIM, 0,0,0, 0);
    k_phm4<<<dim3(2304,NEXP), T256, 0, stream>>>(eA, eS, Wexp_bf, 768, 192, DIM,
                                                 64L, (long)4*768*192, (long)EDIM*DIM, 1);
    // all small weight converts in ONE dispatch
    {
        CJ J;
        J.s[0]=(const float4*)inw;  J.d[0]=(ushort4*)inw_bf;  J.n4[0]=3*QKVC*DIM/4;
        J.s[1]=(const float4*)outw; J.d[1]=(ushort4*)outw_bf; J.n4[1]=3*DD/4;
        J.s[2]=(const float4*)pw;   J.d[2]=(ushort4*)pw_bf;   J.n4[2]=3*DD/4;
        J.s[3]=(const float4*)mem0; J.d[3]=(ushort4*)mem_bf;              J.n4[3]=64*DIM/4;
        J.s[4]=(const float4*)mem1; J.d[4]=(ushort4*)(mem_bf + 64*DIM);   J.n4[4]=128*DIM/4;
        J.s[5]=(const float4*)mem2; J.d[5]=(ushort4*)(mem_bf + 192*DIM);  J.n4[5]=256*DIM/4;
        k_cvt_multi<<<dim3(1024, 6), T256, 0, stream>>>(J);
    }
    // fused fractal out-proj weights: Wc[l] = pw[l] @ outw[l]; bc[l] = pw[l]@outb[l] + pb[l]
    k_bc<<<dim3(DIM/4, 3), T256, 0, stream>>>(pw, outb, pb, bcb);
    k_transw_b<<<dim3(DD/256, 3), T256, 0, stream>>>(outw_bf, wT3_bf);
    {
        L3 dd3 = {0, DD, 2*DD}, z3 = {0,0,0};
        I3 m768 = {DIM, DIM, DIM};
        k_mgemm_b3<2,2,2,1><<<dim3(12,12,3), T256, 0, stream>>>(pw_bf, dd3, DIM, m768,
                                                                wT3_bf, dd3, DIM, DIM, DIM,
                                                                nullptr, z3, Wc_bf, dd3, DIM, 1.f, 0);
    }
    // all 3 fractal K|V projections (mem-side, chain-independent) in ONE dispatch
    {
        L3 xo = {0, 64L*DIM, 192L*DIM};
        L3 wo = {(long)DD, (long)QKVC*DIM + DD, 2L*QKVC*DIM + DD};
        L3 bo = {(long)DIM, (long)QKVC + DIM, 2L*QKVC + DIM};
        L3 co = {0, 256L*2*DIM, 2*256L*2*DIM};
        k_mgemm_b3<1,1,2,1><<<dim3(8,48,3), T64, 0, stream>>>(mem_bf, xo, DIM, Ms3,
                                                              inw_bf, wo, DIM, 2*DIM, DIM,
                                                              inb, bo, kvL_bf, co, 2*DIM, 1.f, 0);
    }
    // Gt[l][j][h*M+m] build (depends on Wc + kvL; chain-independent)
    k_gt<2,2,2,1><<<dim3(12,4,24), T256, 0, stream>>>(Wc_bf, kvL_bf, 256L*2*DIM, Gt_bf, 768L*2048, Ms3);

    // ---- quantum attention ----
    k_mgemm<2,2,2,1><<<dim3(32,36), T256, 0, stream>>>(lnx_bf, DIM, NTOK, Wqkv_bf, DIM, QKVC, DIM,
                                                       qkvb, nullptr, 0, nullptr, qkv_bf, QKVC, 1.f, 0);
    k_transv<<<dim3(8,12,NBATCH), T256, 0, stream>>>(qkv_bf, Vt_bf);
    k_mgemm_qk<2,2,2,1><<<dim3(8,8,48), T256, 0, stream>>>(qkv_bf, scores);
    k_supsoft<<<dim3(NTOK), T256, 0, stream>>>(scores, P_bf, wsup, went);
    k_cvt4<<<4096, T256, 0, stream>>>((const float4*)ndw, (ushort4*)ndw_bf, NEXP*DIM*EDIM/4);
    k_mgemm_pv<1,1,2,1><<<dim3(16,2,48), T64, 0, stream>>>(P_bf, Vt_bf, o_bf);
    k_mgemm<2,2,1,1><<<dim3(64,24), T256, 0, stream>>>(o_bf, DIM, NTOK, Wproj_bf, DIM, DIM, DIM,
                                                       projb, x, DIM, attnd, nullptr, DIM, 1.f, 0);
    // ---- MoE ----
    k_ln<<<NTOK, T256, 0, stream>>>(attnd, ln2g, ln2b, nullptr, lnx_bf);
    k_route<<<NTOK, T256, 0, stream>>>(lnx_bf, Wrout, rb, dr, did, topi, topw, cnt);
    k_prefix<<<1, 1, 0, stream>>>(cnt, prefix);
    k_assign<<<8, T256, 0, stream>>>(topi, prefix, cnt2, rowof, tokof);
    k_gather<<<dim3(1536), T256, 0, stream>>>(lnx_bf, tokof, Xg_bf);
    k_mgemm_expert<2,2,1,1><<<dim3(64,96,NEXP), T256, 0, stream>>>(Xg_bf, DIM, Wexp_bf, DIM, (long)EDIM*DIM,
                                                                   eb, EDIM, prefix, cnt,
                                                                   nullptr, hidden_bf, EDIM, EDIM, DIM, 1);
    k_mgemm_expert<2,2,1,1><<<dim3(64,24,NEXP), T256, 0, stream>>>(hidden_bf, EDIM, ndw_bf, EDIM, (long)DIM*EDIM,
                                                                   ndb, DIM, prefix, cnt,
                                                                   outg, nullptr, DIM, DIM, EDIM, 0);
    k_combine<<<dim3(6144), T256, 0, stream>>>(attnd, outg, rowof, topw, eo, inx_bf);
    // ---- fractal memory (3 levels; K/V + Gt precomputed above; 3 dispatches/level) ----
    int Ms[3] = {64, 128, 256};
    for (int l=0; l<3; ++l){
        const u16* iwl = inw_bf + (size_t)l*QKVC*DIM;
        int M = Ms[l];
        k_mgemm<2,2,1,1><<<dim3(64,24), T256, 0, stream>>>(inx_bf, DIM, NTOK, iwl, DIM, DIM, DIM,
                                                           inb + (size_t)l*QKVC, nullptr, 0, nullptr, qm_bf, DIM, 1.f, 0);
        k_memqk_soft<<<dim3(NTOK/64, MHEADS), T256, 0, stream>>>(qm_bf, kvL_bf + (size_t)l*256*2*DIM, 2*DIM,
                                                                 Pm_bf, M, 0.10206207261596577f);
        // fused PV + (out-proj ∘ proc-proj): a_l = Pcat @ Gt[l]^T + bc ; accum += a_l ; inx_bf = bf16(a_l)
        k_mgemm<2,2,1,1><<<dim3(64,24), T256, 0, stream>>>(Pm_bf, 8*M, NTOK, Gt_bf + (size_t)l*768*2048, 8*M, DIM, 8*M,
                                                           bcb + (size_t)l*DIM, (l==0 ? eo : accum), DIM,
                                                           accum, inx_bf, DIM, 1.f, 0);
    }
    k_ln<<<NTOK, T256, 0, stream>>>(accum, ln3g, ln3b, outf, nullptr);
}

// Round 15
// 595.262 us; speedup vs baseline: 1.0222x; 1.0222x over previous
//
#include <hip/hip_runtime.h>
#include <math.h>

#define DIM    768
#define NTOK   2048
#define NSEQ   512
#define NBATCH 4
#define NHEADS 12
#define HD     64
#define QKVC   2304
#define MHEADS 8
#define MHD    96
#define NEXP   8
#define EDIM   3072
#define DD     (DIM*DIM)

typedef unsigned short u16;
typedef __attribute__((ext_vector_type(8))) short short8;
typedef __attribute__((ext_vector_type(4))) float f32x4;

struct L3 { long a, b, c; };
struct I3 { int a, b, c; };
struct CJ { const float4* s[6]; ushort4* d[6]; int n4[6]; };

__device__ __forceinline__ float gelu_exact(float v){
    return 0.5f * v * (1.f + erff(v * 0.70710678118654752f));
}
__device__ __forceinline__ u16 f2bf(float f){
    unsigned int u = __builtin_bit_cast(unsigned int, f);
    unsigned int r = (u + 0x7FFFu + ((u >> 16) & 1u)) >> 16;
    return (u16)r;
}
__device__ __forceinline__ float bf2f(u16 b){
    unsigned int u = ((unsigned int)b) << 16;
    return __builtin_bit_cast(float, u);
}
__device__ __forceinline__ float fast_tanh(float s){
    return 1.f - 2.f/(__expf(2.f*s) + 1.f);
}
// async global->LDS, 16B per lane; LDS dest linear (wave-uniform base + lane*16)
__device__ __forceinline__ void gll16(const u16* g, u16* l){
    __builtin_amdgcn_global_load_lds((const __attribute__((address_space(1))) void*)g,
                                     (__attribute__((address_space(3))) void*)l, 16, 0, 0);
}

// ================= MFMA bf16 GEMM core =================
// Per-wave tile (16*FR)^2; block tile (WM*16*FR)x(WN*16*FR); BK=64; WM*WN waves.
// DB=1: double-buffered LDS (stage t+1 issued before compute t, ONE barrier/k-step).
// DB=0: single buffer, 2 barriers/k-step.
// R9: counted-vmcnt + extra barrier REGRESSED. R10: 128^2 FR=4 regresses latency-bound experts.
// R12/R13: FR=1 (32x32, 16KB LDS) wins ONLY for wave-starved grids (<~1000 blocks: chain GEMMs,
// down-proj). R14: FR=1 on up-proj (already 12K blocks) REGRESSED — keep FR=2 when grid is large.
// XOR-swizzled LDS via pre-swizzled global SOURCE + linear global_load_lds dest (m201 rule).
template<int WM,int WN,int FR,int DB>
__device__ __forceinline__ void mgemm_core(
    const u16* __restrict__ Xb, int ldx, int rowBase, int rowLim,
    const u16* __restrict__ Wb, int ldw, int colBase, int colLim, int K,
    const float* __restrict__ bias,
    const float* __restrict__ res, int ldres,
    float* __restrict__ Cf, u16* __restrict__ Cb, int ldc,
    float scale, int act)
{
    constexpr int TM = 16*FR;
    constexpr int RM = WM*TM, RN = WN*TM, NT = WM*WN*64;
    constexpr int IA = (RM*8)/NT, IB = (RN*8)/NT;
    constexpr int NB = DB ? 2 : 1;
    __shared__ u16 As[NB][RM*64];
    __shared__ u16 Bs[NB][RN*64];
    int tid = threadIdx.x;
    int lane = tid & 63, w = tid >> 6;
    int wm = (w / WN) * TM, wn = (w % WN) * TM;
    const f32x4 zf = {0.f, 0.f, 0.f, 0.f};
    f32x4 acc[FR][FR];
    #pragma unroll
    for (int i=0;i<FR;i++)
        #pragma unroll
        for (int j=0;j<FR;j++) acc[i][j] = zf;

    const bool fullA = (rowBase + RM <= rowLim);
    const bool fullB = (colBase + RN <= colLim);
    const int nt = (K + 63) >> 6;
    int lr = lane & 15, lk = lane >> 4;

    auto stage = [&](int buf, int k0){
        const bool kfull = (k0 + 64 <= K);
        if (fullA && kfull) {
            #pragma unroll
            for (int it = 0; it < IA; ++it) {
                int idx = it*NT + tid;
                int r = idx >> 3, c = idx & 7;
                gll16(&Xb[(size_t)(rowBase + r)*ldx + k0 + ((c ^ (r & 7)) << 3)], &As[buf][(size_t)idx*8]);
            }
        } else {
            #pragma unroll
            for (int it = 0; it < IA; ++it) {
                int idx = it*NT + tid;
                int r = idx >> 3, c = idx & 7;
                int gr = rowBase + r;
                uint4 v = {0u,0u,0u,0u};
                if (gr < rowLim && (k0 + c*8) < K) v = *(const uint4*)&Xb[(size_t)gr*ldx + k0 + c*8];
                *(uint4*)&As[buf][r*64 + ((c ^ (r & 7)) * 8)] = v;
            }
        }
        if (fullB && kfull) {
            #pragma unroll
            for (int it = 0; it < IB; ++it) {
                int idx = it*NT + tid;
                int r = idx >> 3, c = idx & 7;
                gll16(&Wb[(size_t)(colBase + r)*ldw + k0 + ((c ^ (r & 7)) << 3)], &Bs[buf][(size_t)idx*8]);
            }
        } else {
            #pragma unroll
            for (int it = 0; it < IB; ++it) {
                int idx = it*NT + tid;
                int r = idx >> 3, c = idx & 7;
                int gc = colBase + r;
                uint4 v = {0u,0u,0u,0u};
                if (gc < colLim && (k0 + c*8) < K) v = *(const uint4*)&Wb[(size_t)gc*ldw + k0 + c*8];
                *(uint4*)&Bs[buf][r*64 + ((c ^ (r & 7)) * 8)] = v;
            }
        }
    };
    auto compute = [&](const u16* Ac, const u16* Bc){
        #pragma unroll
        for (int ks = 0; ks < 2; ++ks) {
            short8 af[FR], bfr[FR];
            #pragma unroll
            for (int mi=0; mi<FR; mi++){
                int row = wm + mi*16 + lr;
                int cidx = (ks*4 + lk) ^ (row & 7);
                af[mi] = *(const short8*)&Ac[row*64 + cidx*8];
            }
            #pragma unroll
            for (int ni=0; ni<FR; ni++){
                int col = wn + ni*16 + lr;
                int cidx = (ks*4 + lk) ^ (col & 7);
                bfr[ni] = *(const short8*)&Bc[col*64 + cidx*8];
            }
            #pragma unroll
            for (int mi=0; mi<FR; mi++)
                #pragma unroll
                for (int ni=0; ni<FR; ni++)
                    acc[mi][ni] = __builtin_amdgcn_mfma_f32_16x16x32_bf16(af[mi], bfr[ni], acc[mi][ni], 0, 0, 0);
        }
    };

    if (DB) {
        stage(0, 0);
        __syncthreads();
        for (int t = 0; t < nt; ++t) {
            if (t + 1 < nt) stage((t+1)&1, (t+1)*64);
            compute(As[t&1], Bs[t&1]);
            __syncthreads();
        }
    } else {
        for (int t = 0; t < nt; ++t) {
            stage(0, t*64);
            __syncthreads();
            compute(As[0], Bs[0]);
            __syncthreads();
        }
    }
    // epilogue: D row = (lane>>4)*4 + reg, col = lane&15  [m89-verified]
    int lg = lane >> 4;
    #pragma unroll
    for (int mi=0; mi<FR; mi++){
        #pragma unroll
        for (int r=0; r<4; r++){
            int row = rowBase + wm + mi*16 + lg*4 + r;
            if (row >= rowLim) continue;
            #pragma unroll
            for (int ni=0; ni<FR; ni++){
                int col = colBase + wn + ni*16 + lr;
                if (col >= colLim) continue;
                float v = acc[mi][ni][r] * scale;
                if (bias) v += bias[col];
                if (act == 1) v = gelu_exact(v);
                if (Cb) Cb[(size_t)row*ldc + col] = f2bf(v);
                if (res) v += res[(size_t)row*ldres + col];
                if (Cf) Cf[(size_t)row*ldc + col] = v;
            }
        }
    }
}

template<int WM,int WN,int FR,int DB>
__global__ __launch_bounds__(WM*WN*64) void k_mgemm(
    const u16* __restrict__ X, int ldx, int M,
    const u16* __restrict__ W, int ldw, int N, int K,
    const float* __restrict__ bias, const float* __restrict__ res, int ldres,
    float* __restrict__ Cf, u16* __restrict__ Cb, int ldc, float scale, int act)
{
    constexpr int RM = WM*16*FR, RN = WN*16*FR;
    mgemm_core<WM,WN,FR,DB>(X, ldx, blockIdx.x*RM, M, W, ldw, blockIdx.y*RN, N, K,
                            bias, res, ldres, Cf, Cb, ldc, scale, act);
}

// batched-by-3 variant: z selects offsets into X/W/bias/C and M
template<int WM,int WN,int FR,int DB>
__global__ __launch_bounds__(WM*WN*64) void k_mgemm_b3(
    const u16* __restrict__ X, L3 xo, int ldx, I3 Mv,
    const u16* __restrict__ W, L3 wo, int ldw, int N, int K,
    const float* __restrict__ bias, L3 bo,
    u16* __restrict__ Cb, L3 co, int ldc, float scale, int act)
{
    constexpr int RM = WM*16*FR, RN = WN*16*FR;
    int z = blockIdx.z;
    int M    = (z==0) ? Mv.a : (z==1) ? Mv.b : Mv.c;
    long xof = (z==0) ? xo.a : (z==1) ? xo.b : xo.c;
    long wof = (z==0) ? wo.a : (z==1) ? wo.b : wo.c;
    long bof = (z==0) ? bo.a : (z==1) ? bo.b : bo.c;
    long cof = (z==0) ? co.a : (z==1) ? co.b : co.c;
    if ((int)blockIdx.x * RM >= M) return;
    mgemm_core<WM,WN,FR,DB>(X + xof, ldx, blockIdx.x*RM, M, W + wof, ldw, blockIdx.y*RN, N, K,
                            bias ? bias + bof : nullptr, nullptr, 0, nullptr, Cb + cof, ldc, scale, act);
}

template<int WM,int WN,int FR,int DB>
__global__ __launch_bounds__(WM*WN*64) void k_mgemm_expert(
    const u16* __restrict__ X, int ldx,
    const u16* __restrict__ Wb, int ldw, long wStride,
    const float* __restrict__ biasB, int biasStride,
    const int* __restrict__ prefix, const int* __restrict__ cnt,
    float* __restrict__ Cf, u16* __restrict__ Cb, int ldc, int N, int K, int act)
{
    constexpr int RM = WM*16*FR, RN = WN*16*FR;
    int e = blockIdx.z;
    int n = cnt[e];
    if ((int)blockIdx.x * RM >= n) return;
    mgemm_core<WM,WN,FR,DB>(X, ldx, prefix[e] + blockIdx.x*RM, prefix[e] + n,
                            Wb + (size_t)e*wStride, ldw, blockIdx.y*RN, N, K,
                            biasB + (size_t)e*biasStride, nullptr, 0, Cf, Cb, ldc, 1.f, act);
}

// scores[b,h,n,m] = 0.125 * q_n . k_m  (bf16 out)
template<int WM,int WN,int FR,int DB>
__global__ __launch_bounds__(WM*WN*64) void k_mgemm_qk(const u16* __restrict__ qkv, u16* __restrict__ attn)
{
    constexpr int RM = WM*16*FR, RN = WN*16*FR;
    int z = blockIdx.z, b = z / NHEADS, h = z % NHEADS;
    const u16* X = qkv + (size_t)b*NSEQ*QKVC + h*HD;          // q
    const u16* W = qkv + (size_t)b*NSEQ*QKVC + DIM + h*HD;    // k
    u16* C = attn + (size_t)z*NSEQ*NSEQ;
    mgemm_core<WM,WN,FR,DB>(X, QKVC, blockIdx.x*RM, NSEQ, W, QKVC, blockIdx.y*RN, NSEQ, HD,
                            nullptr, nullptr, 0, nullptr, C, NSEQ, 0.125f, 0);
}

// o[b,n,h*64+d] = sum_m P[b,h,n,m] * V[b,m,h*64+d]; Vt[b][d][m] supplies W
template<int WM,int WN,int FR,int DB>
__global__ __launch_bounds__(WM*WN*64) void k_mgemm_pv(const u16* __restrict__ P, const u16* __restrict__ Vt, u16* __restrict__ o)
{
    constexpr int RM = WM*16*FR, RN = WN*16*FR;
    int z = blockIdx.z, b = z / NHEADS, h = z % NHEADS;
    const u16* X = P + (size_t)z*NSEQ*NSEQ;
    const u16* W = Vt + ((size_t)b*DIM + h*HD)*NSEQ;
    u16* C = o + (size_t)b*NSEQ*DIM + h*HD;
    mgemm_core<WM,WN,FR,DB>(X, NSEQ, blockIdx.x*RM, NSEQ, W, NSEQ, blockIdx.y*RN, HD, NSEQ,
                            nullptr, nullptr, 0, nullptr, C, DIM, 1.f, 0);
}

// ===== Gt build: Gt[l][j][h*M+m] = sum_d Wc[l][j][h*96+d] * V[l][m][h*96+d] =====
template<int WM,int WN,int FR,int DB>
__global__ __launch_bounds__(WM*WN*64) void k_gt(
    const u16* __restrict__ Wc, const u16* __restrict__ kvL, long kvStride,
    u16* __restrict__ Gt, long gtStride, I3 Mv)
{
    constexpr int RM = WM*16*FR, RN = WN*16*FR;
    int z = blockIdx.z, l = z >> 3, h = z & 7;
    int M = (l==0) ? Mv.a : (l==1) ? Mv.b : Mv.c;
    if ((int)blockIdx.y * RN >= M) return;
    mgemm_core<WM,WN,FR,DB>(Wc + (size_t)l*DD + h*MHD, DIM, blockIdx.x*RM, DIM,
                            kvL + (size_t)l*kvStride + DIM + h*MHD, 2*DIM, blockIdx.y*RN, M, MHD,
                            nullptr, nullptr, 0, nullptr,
                            Gt + (size_t)l*gtStride + (size_t)h*M, 8*M, 1.f, 0);
}

// ===== fused mem-MHA scores + row softmax: block = 64 q-rows x full M (<=256), 4 waves =====
// writes P[n][h*M+m] (token-major) so the PV+proj GEMM consumes it as one (2048 x 8M) operand
__global__ __launch_bounds__(256) void k_memqk_soft(
    const u16* __restrict__ q, const u16* __restrict__ kv, int ldk,
    u16* __restrict__ P, int M, float scale)
{
    constexpr int RM = 64, RN = 256, NT = 256, K = MHD;
    __shared__ u16 As[RM*64];
    __shared__ u16 Bs[RN*64];
    __shared__ float red0[RM][4];
    __shared__ float red1[RM][4];
    int h = blockIdx.y;
    int rowBase = blockIdx.x * RM;
    const u16* Xb = q + h*MHD;     // ldx = DIM
    const u16* Wb = kv + h*MHD;    // ldw = ldk
    int tid = threadIdx.x, lane = tid & 63, w = tid >> 6;
    int wn = w * 64;
    int lr = lane & 15, lk = lane >> 4;
    const f32x4 zf = {0.f,0.f,0.f,0.f};
    f32x4 acc[4][4];
    #pragma unroll
    for (int i=0;i<4;i++)
        #pragma unroll
        for (int j=0;j<4;j++) acc[i][j] = zf;

    for (int k0 = 0; k0 < K; k0 += 64) {
        const bool kfull = (k0 + 64 <= K);
        if (kfull) {
            #pragma unroll
            for (int it = 0; it < 2; ++it) {
                int idx = it*NT + tid;
                int r = idx >> 3, c = idx & 7;
                gll16(&Xb[(size_t)(rowBase + r)*DIM + k0 + ((c ^ (r & 7)) << 3)], &As[(size_t)idx*8]);
            }
        } else {
            #pragma unroll
            for (int it = 0; it < 2; ++it) {
                int idx = it*NT + tid;
                int r = idx >> 3, c = idx & 7;
                uint4 v = {0u,0u,0u,0u};
                if ((k0 + c*8) < K) v = *(const uint4*)&Xb[(size_t)(rowBase + r)*DIM + k0 + c*8];
                *(uint4*)&As[r*64 + ((c ^ (r & 7)) * 8)] = v;
            }
        }
        #pragma unroll
        for (int it = 0; it < 8; ++it) {
            int idx = it*NT + tid;
            int r = idx >> 3, c = idx & 7;
            uint4 v = {0u,0u,0u,0u};
            if (r < M && (k0 + c*8) < K) v = *(const uint4*)&Wb[(size_t)r*ldk + k0 + c*8];
            *(uint4*)&Bs[r*64 + ((c ^ (r & 7)) * 8)] = v;
        }
        __syncthreads();
        #pragma unroll
        for (int ks = 0; ks < 2; ++ks) {
            short8 af[4], bfr[4];
            #pragma unroll
            for (int mi=0; mi<4; mi++){
                int row = mi*16 + lr;
                int cidx = (ks*4 + lk) ^ (row & 7);
                af[mi] = *(const short8*)&As[row*64 + cidx*8];
            }
            #pragma unroll
            for (int ni=0; ni<4; ni++){
                int col = wn + ni*16 + lr;
                int cidx = (ks*4 + lk) ^ (col & 7);
                bfr[ni] = *(const short8*)&Bs[col*64 + cidx*8];
            }
            #pragma unroll
            for (int mi=0; mi<4; mi++)
                #pragma unroll
                for (int ni=0; ni<4; ni++)
                    acc[mi][ni] = __builtin_amdgcn_mfma_f32_16x16x32_bf16(af[mi], bfr[ni], acc[mi][ni], 0, 0, 0);
        }
        __syncthreads();
    }
    int lg = lane >> 4;
    float sc[4][4][4];
    float rmax[4][4];
    #pragma unroll
    for (int mi=0; mi<4; mi++){
        #pragma unroll
        for (int r=0; r<4; r++){
            float m = -1e30f;
            #pragma unroll
            for (int ni=0; ni<4; ni++){
                int col = wn + ni*16 + lr;
                float v = (col < M) ? acc[mi][ni][r]*scale : -1e30f;
                sc[mi][r][ni] = v;
                m = fmaxf(m, v);
            }
            m = fmaxf(m, __shfl_xor(m, 1));
            m = fmaxf(m, __shfl_xor(m, 2));
            m = fmaxf(m, __shfl_xor(m, 4));
            m = fmaxf(m, __shfl_xor(m, 8));
            rmax[mi][r] = m;
        }
    }
    if (lr == 0){
        #pragma unroll
        for (int mi=0; mi<4; mi++)
            #pragma unroll
            for (int r=0; r<4; r++) red0[mi*16 + lg*4 + r][w] = rmax[mi][r];
    }
    __syncthreads();
    float gmax[4][4], rsum[4][4];
    #pragma unroll
    for (int mi=0; mi<4; mi++){
        #pragma unroll
        for (int r=0; r<4; r++){
            int row = mi*16 + lg*4 + r;
            float g = fmaxf(fmaxf(red0[row][0], red0[row][1]), fmaxf(red0[row][2], red0[row][3]));
            gmax[mi][r] = g;
            float s = 0.f;
            #pragma unroll
            for (int ni=0; ni<4; ni++){
                int col = wn + ni*16 + lr;
                if (col < M) s += __expf(sc[mi][r][ni] - g);
            }
            s += __shfl_xor(s, 1);
            s += __shfl_xor(s, 2);
            s += __shfl_xor(s, 4);
            s += __shfl_xor(s, 8);
            rsum[mi][r] = s;
        }
    }
    if (lr == 0){
        #pragma unroll
        for (int mi=0; mi<4; mi++)
            #pragma unroll
            for (int r=0; r<4; r++) red1[mi*16 + lg*4 + r][w] = rsum[mi][r];
    }
    __syncthreads();
    #pragma unroll
    for (int mi=0; mi<4; mi++){
        #pragma unroll
        for (int r=0; r<4; r++){
            int row = mi*16 + lg*4 + r;
            float tot = red1[row][0] + red1[row][1] + red1[row][2] + red1[row][3];
            float inv = 1.f / tot;
            #pragma unroll
            for (int ni=0; ni<4; ni++){
                int col = wn + ni*16 + lr;
                if (col < M)
                    P[(((size_t)(rowBase + row))*MHEADS + h)*M + col] = f2bf(__expf(sc[mi][r][ni] - gmax[mi][r]) * inv);
            }
        }
    }
}

// batched outw transpose: wT3[z][c][r] = outw[z][r][c]
__global__ __launch_bounds__(256) void k_transw_b(const u16* __restrict__ src, u16* __restrict__ dst)
{
    int z = blockIdx.y;
    int idx = blockIdx.x*256 + threadIdx.x;
    int r = idx / DIM, c = idx % DIM;
    dst[(size_t)z*DD + (size_t)c*DIM + r] = src[(size_t)z*DD + (size_t)r*DIM + c];
}

// ================= PHM weight materialization, 4-wide (Si divisible by 4) =================
__global__ __launch_bounds__(256) void k_phm4(
    const float* __restrict__ A, const float* __restrict__ S, void* __restrict__ W,
    int So, int Si, int inF, long Astride, long Sstride, long Wstride, int obf)
{
    int e = blockIdx.y;
    const float* Ae = A + (size_t)e*Astride;
    const float* Se = S + (size_t)e*Sstride;
    size_t idx = (size_t)blockIdx.x*256 + threadIdx.x;
    int inF4 = inF >> 2;
    size_t total = (size_t)(So*4) * inF4;
    if (idx >= total) return;
    int in4 = (int)(idx % inF4);
    int o   = (int)(idx / inF4);
    int a = o / So, c = o % So;
    int in0 = in4 * 4;
    int b = in0 / Si, d = in0 % Si;
    float4 acc = {0.f,0.f,0.f,0.f};
    #pragma unroll
    for (int i=0;i<4;i++){
        float av = Ae[i*16 + a*4 + b];
        float4 sv = *(const float4*)&Se[((size_t)i*So + c)*Si + d];
        acc.x = fmaf(av, sv.x, acc.x);
        acc.y = fmaf(av, sv.y, acc.y);
        acc.z = fmaf(av, sv.z, acc.z);
        acc.w = fmaf(av, sv.w, acc.w);
    }
    size_t oidx = (size_t)o*inF + in0;
    if (obf){
        ushort4 r; r.x=f2bf(acc.x); r.y=f2bf(acc.y); r.z=f2bf(acc.z); r.w=f2bf(acc.w);
        *(ushort4*)&((u16*)W)[(size_t)e*Wstride + oidx] = r;
    } else {
        *(float4*)&((float*)W)[(size_t)e*Wstride + oidx] = acc;
    }
}

// ================= fp32 -> bf16 converts =================
__global__ __launch_bounds__(256) void k_cvt4(const float4* __restrict__ s, ushort4* __restrict__ d, int n4)
{
    for (int i = blockIdx.x*256 + threadIdx.x; i < n4; i += gridDim.x*256){
        float4 v = s[i];
        ushort4 o; o.x = f2bf(v.x); o.y = f2bf(v.y); o.z = f2bf(v.z); o.w = f2bf(v.w);
        d[i] = o;
    }
}
__global__ __launch_bounds__(256) void k_cvt_multi(CJ J)
{
    int z = blockIdx.y;
    const float4* s = J.s[z]; ushort4* d = J.d[z]; int n4 = J.n4[z];
    for (int i = blockIdx.x*256 + threadIdx.x; i < n4; i += gridDim.x*256){
        float4 v = s[i];
        ushort4 o; o.x = f2bf(v.x); o.y = f2bf(v.y); o.z = f2bf(v.z); o.w = f2bf(v.w);
        d[i] = o;
    }
}

// bc[l][i] = dot(pw[l][i][:], outb[l][:]) + pb[l][i]
__global__ __launch_bounds__(256) void k_bc(const float* __restrict__ pw, const float* __restrict__ outb,
                                            const float* __restrict__ pb, float* __restrict__ bc)
{
    int l = blockIdx.y;
    int i = blockIdx.x*4 + (threadIdx.x >> 6);
    int lane = threadIdx.x & 63;
    const float* pr = pw + ((size_t)l*DIM + i)*DIM;
    const float* ob = outb + (size_t)l*DIM;
    float s = 0.f;
    for (int j = lane; j < DIM; j += 64) s = fmaf(pr[j], ob[j], s);
    for (int off=32; off; off>>=1) s += __shfl_xor(s, off);
    if (lane == 0) bc[(size_t)l*DIM + i] = s + pb[(size_t)l*DIM + i];
}

// ================= LayerNorm (row=768), dual output =================
__global__ __launch_bounds__(256) void k_ln(const float* __restrict__ x, const float* __restrict__ g,
                                            const float* __restrict__ b,
                                            float* __restrict__ yf, u16* __restrict__ yb)
{
    int row = blockIdx.x, tid = threadIdx.x;
    const float* xr = x + (size_t)row * DIM;
    float v0 = xr[tid], v1 = xr[tid+256], v2 = xr[tid+512];
    float s = v0+v1+v2;
    float ss = v0*v0 + v1*v1 + v2*v2;
    for (int off=32; off; off>>=1){ s += __shfl_xor(s,off); ss += __shfl_xor(ss,off); }
    __shared__ float sa[4], sb[4];
    int wid = tid >> 6;
    if ((tid & 63) == 0){ sa[wid]=s; sb[wid]=ss; }
    __syncthreads();
    s  = sa[0]+sa[1]+sa[2]+sa[3];
    ss = sb[0]+sb[1]+sb[2]+sb[3];
    float mean = s * (1.f/DIM);
    float var  = ss * (1.f/DIM) - mean*mean;
    float rstd = rsqrtf(var + 1e-5f);
    float o0 = (v0-mean)*rstd*g[tid]     + b[tid];
    float o1 = (v1-mean)*rstd*g[tid+256] + b[tid+256];
    float o2 = (v2-mean)*rstd*g[tid+512] + b[tid+512];
    if (yf){ float* yr = yf + (size_t)row*DIM; yr[tid]=o0; yr[tid+256]=o1; yr[tid+512]=o2; }
    if (yb){ u16* yr = yb + (size_t)row*DIM; yr[tid]=f2bf(o0); yr[tid+256]=f2bf(o1); yr[tid+512]=f2bf(o2); }
}

// ===== fused sup/ent mix + tanh + softmax (bf16 scores in, uint4 loads): block per (b,n) =====
__global__ __launch_bounds__(256) void k_supsoft(
    const u16* __restrict__ attn, u16* __restrict__ P,
    const float* __restrict__ wsup, const float* __restrict__ went)
{
    __shared__ float S[NHEADS][NSEQ];
    __shared__ float ws[144], we[144];
    int bn = blockIdx.x;
    int b = bn >> 9, n = bn & 511;
    int tid = threadIdx.x;
    if (tid < 144){ ws[tid] = wsup[tid]; we[tid] = went[tid]; }
    size_t base = ((size_t)b*NHEADS*NSEQ + n)*NSEQ;
    #pragma unroll
    for (int it=0; it<3; ++it){
        int idx = it*256 + tid;
        int j = idx >> 6, m8 = (idx & 63) * 8;
        uint4 v = *(const uint4*)&attn[base + (size_t)j*NSEQ*NSEQ + m8];
        S[j][m8+0] = bf2f((u16)(v.x & 0xFFFFu)); S[j][m8+1] = bf2f((u16)(v.x >> 16));
        S[j][m8+2] = bf2f((u16)(v.y & 0xFFFFu)); S[j][m8+3] = bf2f((u16)(v.y >> 16));
        S[j][m8+4] = bf2f((u16)(v.z & 0xFFFFu)); S[j][m8+5] = bf2f((u16)(v.z >> 16));
        S[j][m8+6] = bf2f((u16)(v.w & 0xFFFFu)); S[j][m8+7] = bf2f((u16)(v.w >> 16));
    }
    __syncthreads();
    #pragma unroll
    for (int half=0; half<2; ++half){
        int m = tid + half*256;
        float av[12], sup[12];
        #pragma unroll
        for (int j=0;j<12;j++) av[j] = S[j][m];
        #pragma unroll
        for (int i=0;i<12;i++){
            float s = 0.f;
            #pragma unroll
            for (int j=0;j<12;j++) s = fmaf(ws[i*12+j], av[j], s);
            sup[i] = s;
        }
        #pragma unroll
        for (int i=0;i<12;i++){
            float s = sup[i];
            #pragma unroll
            for (int j=0;j<12;j++) s = fmaf(we[i*12+j], sup[j], s);
            av[i] = fast_tanh(s);
        }
        #pragma unroll
        for (int i=0;i<12;i++) S[i][m] = av[i];
    }
    __syncthreads();
    int lane = tid & 63, wv = tid >> 6;
    #pragma unroll
    for (int jj=0; jj<3; ++jj){
        int j = wv*3 + jj;
        float v[8], mx = -1e30f;
        #pragma unroll
        for (int k=0;k<8;k++){ v[k] = S[j][lane + 64*k]; mx = fmaxf(mx, v[k]); }
        for (int off=32; off; off>>=1) mx = fmaxf(mx, __shfl_xor(mx, off));
        float sum = 0.f;
        #pragma unroll
        for (int k=0;k<8;k++){ v[k] = __expf(v[k]-mx); sum += v[k]; }
        for (int off=32; off; off>>=1) sum += __shfl_xor(sum, off);
        float inv = 1.f/sum;
        #pragma unroll
        for (int k=0;k<8;k++) P[base + (size_t)j*NSEQ*NSEQ + lane + 64*k] = f2bf(v[k]*inv);
    }
}

// ================= V transpose (main attn): Vt[b][d][m] = qkv_bf[b][m][1536+d] =================
__global__ __launch_bounds__(256) void k_transv(const u16* __restrict__ qkv, u16* __restrict__ Vt)
{
    __shared__ u16 L[64][65];
    int mt = blockIdx.x*64, dt = blockIdx.y*64, b = blockIdx.z;
    int tid = threadIdx.x;
    #pragma unroll
    for (int it=0; it<16; ++it){
        int idx = it*256 + tid;
        int mm = idx >> 6, dd = idx & 63;
        L[mm][dd] = qkv[((size_t)b*NSEQ + mt + mm)*QKVC + 1536 + dt + dd];
    }
    __syncthreads();
    #pragma unroll
    for (int it=0; it<16; ++it){
        int idx = it*256 + tid;
        int dd = idx >> 6, mm = idx & 63;
        Vt[((size_t)b*DIM + dt + dd)*NSEQ + mt + mm] = L[mm][dd];
    }
}

// ================= MoE routing (bf16 input) =================
__global__ __launch_bounds__(256) void k_route(
    const u16* __restrict__ ln2, const float* __restrict__ Wr,
    const float* __restrict__ rb, const float* __restrict__ dr,
    const int* __restrict__ did, int* __restrict__ topi, float* __restrict__ topw, int* __restrict__ cnt)
{
    int t = blockIdx.x, tid = threadIdx.x;
    const u16* xr = ln2 + (size_t)t*DIM;
    float a[8] = {};
    #pragma unroll
    for (int ii=0; ii<3; ii++){
        int i = tid + ii*256;
        float xv = bf2f(xr[i]);
        #pragma unroll
        for (int e=0;e<8;e++) a[e] = fmaf(xv, Wr[e*DIM + i], a[e]);
    }
    #pragma unroll
    for (int e=0;e<8;e++)
        for (int off=32; off; off>>=1) a[e] += __shfl_xor(a[e], off);
    __shared__ float sred[4][8];
    int wid = tid >> 6;
    if ((tid & 63) == 0){
        #pragma unroll
        for (int e=0;e<8;e++) sred[wid][e] = a[e];
    }
    __syncthreads();
    if (tid == 0){
        int d = did[0];
        float lg[8];
        #pragma unroll
        for (int e=0;e<8;e++) lg[e] = sred[0][e]+sred[1][e]+sred[2][e]+sred[3][e] + rb[e] + dr[d*8+e];
        int i1 = 0; float v1 = lg[0];
        #pragma unroll
        for (int e=1;e<8;e++) if (lg[e] > v1){ v1 = lg[e]; i1 = e; }
        int i2 = -1; float v2 = -1e30f;
        #pragma unroll
        for (int e=0;e<8;e++) if (e != i1 && lg[e] > v2){ v2 = lg[e]; i2 = e; }
        float e2 = __expf(v2 - v1);
        float inv = 1.f / (1.f + e2);
        topi[2*t] = i1; topi[2*t+1] = i2;
        topw[2*t] = inv; topw[2*t+1] = e2 * inv;
        atomicAdd(&cnt[i1], 1); atomicAdd(&cnt[i2], 1);
    }
}

__global__ void k_zero(int* p, int n){ int i = threadIdx.x; if (i < n) p[i] = 0; }

__global__ void k_prefix(const int* __restrict__ cnt, int* __restrict__ prefix){
    if (threadIdx.x == 0){ int s=0; for (int e=0;e<8;e++){ prefix[e]=s; s+=cnt[e]; } }
}

__global__ __launch_bounds__(256) void k_assign(
    const int* __restrict__ topi, const int* __restrict__ prefix,
    int* __restrict__ cnt2, int* __restrict__ rowof, int* __restrict__ tokof)
{
    int t = blockIdx.x*256 + threadIdx.x;
    if (t >= NTOK) return;
    #pragma unroll
    for (int k=0;k<2;k++){
        int e = topi[2*t+k];
        int slot = atomicAdd(&cnt2[e], 1);
        int row = prefix[e] + slot;
        rowof[2*t+k] = row;
        tokof[row] = t;
    }
}

// 16B-vectorized gather
__global__ __launch_bounds__(256) void k_gather(const u16* __restrict__ src, const int* __restrict__ tokof, u16* __restrict__ dst)
{
    int i = blockIdx.x*256 + threadIdx.x;
    int row = i / 96, c = (i % 96) * 8;
    *(uint4*)&dst[(size_t)row*DIM + c] = *(const uint4*)&src[(size_t)tokof[row]*DIM + c];
}

__global__ __launch_bounds__(256) void k_combine(
    const float* __restrict__ att, const float* __restrict__ outg,
    const int* __restrict__ rowof, const float* __restrict__ topw,
    float* __restrict__ eo, u16* __restrict__ eob)
{
    size_t i = (size_t)blockIdx.x*256 + threadIdx.x;
    int t = (int)(i / DIM), c = (int)(i % DIM);
    int r0 = rowof[2*t], r1 = rowof[2*t+1];
    float v = att[i] + topw[2*t]*outg[(size_t)r0*DIM+c] + topw[2*t+1]*outg[(size_t)r1*DIM+c];
    eo[i] = v;
    eob[i] = f2bf(v);
}

// ================= host =================
extern "C" void kernel_launch(void* const* d_in, const int* in_sizes, int n_in,
                              void* d_out, int out_size, void* d_ws, size_t ws_size,
                              hipStream_t stream)
{
    const float* x     = (const float*)d_in[0];
    const float* ln1g  = (const float*)d_in[1];
    const float* ln1b  = (const float*)d_in[2];
    const float* ln2g  = (const float*)d_in[3];
    const float* ln2b  = (const float*)d_in[4];
    const float* ln3g  = (const float*)d_in[5];
    const float* ln3b  = (const float*)d_in[6];
    const float* qkvA  = (const float*)d_in[7];
    const float* qkvS  = (const float*)d_in[8];
    const float* qkvb  = (const float*)d_in[9];
    const float* projA = (const float*)d_in[10];
    const float* projS = (const float*)d_in[11];
    const float* projb = (const float*)d_in[12];
    const float* wsup  = (const float*)d_in[13];
    const float* went  = (const float*)d_in[14];
    const float* rA    = (const float*)d_in[15];
    const float* rS    = (const float*)d_in[16];
    const float* rb    = (const float*)d_in[17];
    const float* dr    = (const float*)d_in[18];
    const float* eA    = (const float*)d_in[19];
    const float* eS    = (const float*)d_in[20];
    const float* eb    = (const float*)d_in[21];
    const float* ndw   = (const float*)d_in[22];
    const float* ndb   = (const float*)d_in[23];
    const float* mem0  = (const float*)d_in[24];
    const float* mem1  = (const float*)d_in[25];
    const float* mem2  = (const float*)d_in[26];
    const float* inw   = (const float*)d_in[27];
    const float* inb   = (const float*)d_in[28];
    const float* outw  = (const float*)d_in[29];
    const float* outb  = (const float*)d_in[30];
    const float* pw    = (const float*)d_in[31];
    const float* pb    = (const float*)d_in[32];
    const int*   did   = (const int*)d_in[33];

    float* f = (float*)d_ws;
    size_t off = 0;
    auto alloc = [&](size_t n){ float* p = f + off; off += (n + 3) & ~(size_t)3; return p; };
    auto allocb = [&](size_t n){ return (u16*)alloc((n + 1) / 2); };

    // fp32 buffers
    float* attnd  = alloc((size_t)NTOK*DIM);
    float* eo     = alloc((size_t)NTOK*DIM);
    float* accum  = alloc((size_t)NTOK*DIM);
    float* attnb  = alloc((size_t)48*NSEQ*NSEQ);   // u16 scores; hosts outg + ndw_bf
    float* Wrout  = alloc((size_t)NEXP*DIM);
    float* topw   = alloc((size_t)2*NTOK);
    float* bcb    = alloc((size_t)3*DIM);
    int* ip = (int*)alloc((size_t)6*NTOK + 64);
    int* topi   = ip;            ip += 2*NTOK;
    int* rowof  = ip;            ip += 2*NTOK;
    int* tokof  = ip;            ip += 2*NTOK;
    int* cnt    = ip;            ip += 8;
    int* cnt2   = ip;            ip += 8;
    int* prefix = ip;            ip += 8;

    // aliases inside attnb (scores dead after supsoft)
    u16*   scores = (u16*)attnb;                         // 48*512*512 u16
    float* outg   = attnb;                               // 4096x768 fp32 (MoE)
    u16*   ndw_bf = (u16*)(attnb + (size_t)3146240);     // 18.87M u16 (MoE)

    // bf16 buffers
    u16* Wqkv_bf  = allocb((size_t)QKVC*DIM);
    u16* Wproj_bf = allocb((size_t)DD);
    u16* Wexp_bf  = allocb((size_t)NEXP*EDIM*DIM);
    u16* inw_bf   = allocb((size_t)3*QKVC*DIM);
    u16* outw_bf  = allocb((size_t)3*DD);
    u16* pw_bf    = allocb((size_t)3*DD);
    u16* Wc_bf    = allocb((size_t)3*DD);
    u16* wT3_bf   = allocb((size_t)3*DD);
    u16* mem_bf   = allocb((size_t)448*DIM);
    u16* qkv_bf   = allocb((size_t)NTOK*QKVC);     // hosts Xg_bf later
    u16* Vt_bf    = allocb((size_t)NBATCH*DIM*NSEQ);
    u16* P_bf     = allocb((size_t)48*NSEQ*NSEQ);  // also hidden_bf, later Pm_bf
    u16* lnx_bf   = allocb((size_t)NTOK*DIM);
    u16* o_bf     = allocb((size_t)NTOK*DIM);      // attn out; later qm_bf
    u16* inx_bf   = allocb((size_t)NTOK*DIM);
    u16* kvL_bf   = allocb((size_t)3*256*2*DIM);   // [3][256][1536] fused K|V per level
    u16* Gt_bf    = allocb((size_t)3*768*2048);    // [3][768][8*M_l] fused PV+proj weights
    u16* Xg_bf    = qkv_bf;
    u16* hidden_bf= P_bf;
    u16* Pm_bf    = P_bf;
    u16* qm_bf    = o_bf;

    float* outf = (float*)d_out;
    dim3 T256(256), T64(64);
    I3 Ms3 = {64, 128, 256};

    k_zero<<<1, 32, 0, stream>>>(cnt, 16);
    k_ln<<<NTOK, T256, 0, stream>>>(x, ln1g, ln1b, nullptr, lnx_bf);
    // PHM weight builds (bf16 except router), 4-wide
    k_phm4<<<dim3(1728,1), T256, 0, stream>>>(qkvA, qkvS, Wqkv_bf, 576, 192, DIM, 0,0,0, 1);
    k_phm4<<<dim3(576,1),  T256, 0, stream>>>(projA, projS, Wproj_bf, 192, 192, DIM, 0,0,0, 1);
    k_phm4<<<dim3(6,1),    T256, 0, stream>>>(rA, rS, Wrout, 2, 192, DIM, 0,0,0, 0);
    k_phm4<<<dim3(2304,NEXP), T256, 0, stream>>>(eA, eS, Wexp_bf, 768, 192, DIM,
                                                 64L, (long)4*768*192, (long)EDIM*DIM, 1);
    // all small weight converts in ONE dispatch
    {
        CJ J;
        J.s[0]=(const float4*)inw;  J.d[0]=(ushort4*)inw_bf;  J.n4[0]=3*QKVC*DIM/4;
        J.s[1]=(const float4*)outw; J.d[1]=(ushort4*)outw_bf; J.n4[1]=3*DD/4;
        J.s[2]=(const float4*)pw;   J.d[2]=(ushort4*)pw_bf;   J.n4[2]=3*DD/4;
        J.s[3]=(const float4*)mem0; J.d[3]=(ushort4*)mem_bf;              J.n4[3]=64*DIM/4;
        J.s[4]=(const float4*)mem1; J.d[4]=(ushort4*)(mem_bf + 64*DIM);   J.n4[4]=128*DIM/4;
        J.s[5]=(const float4*)mem2; J.d[5]=(ushort4*)(mem_bf + 192*DIM);  J.n4[5]=256*DIM/4;
        k_cvt_multi<<<dim3(1024, 6), T256, 0, stream>>>(J);
    }
    // fused fractal out-proj weights: Wc[l] = pw[l] @ outw[l]; bc[l] = pw[l]@outb[l] + pb[l]
    k_bc<<<dim3(DIM/4, 3), T256, 0, stream>>>(pw, outb, pb, bcb);
    k_transw_b<<<dim3(DD/256, 3), T256, 0, stream>>>(outw_bf, wT3_bf);
    {
        L3 dd3 = {0, DD, 2*DD}, z3 = {0,0,0};
        I3 m768 = {DIM, DIM, DIM};
        k_mgemm_b3<2,2,2,1><<<dim3(12,12,3), T256, 0, stream>>>(pw_bf, dd3, DIM, m768,
                                                                wT3_bf, dd3, DIM, DIM, DIM,
                                                                nullptr, z3, Wc_bf, dd3, DIM, 1.f, 0);
    }
    // all 3 fractal K|V projections (mem-side, chain-independent) in ONE dispatch
    {
        L3 xo = {0, 64L*DIM, 192L*DIM};
        L3 wo = {(long)DD, (long)QKVC*DIM + DD, 2L*QKVC*DIM + DD};
        L3 bo = {(long)DIM, (long)QKVC + DIM, 2L*QKVC + DIM};
        L3 co = {0, 256L*2*DIM, 2*256L*2*DIM};
        k_mgemm_b3<1,1,2,1><<<dim3(8,48,3), T64, 0, stream>>>(mem_bf, xo, DIM, Ms3,
                                                              inw_bf, wo, DIM, 2*DIM, DIM,
                                                              inb, bo, kvL_bf, co, 2*DIM, 1.f, 0);
    }
    // Gt[l][j][h*M+m] build (depends on Wc + kvL; chain-independent)
    k_gt<2,2,2,1><<<dim3(12,4,24), T256, 0, stream>>>(Wc_bf, kvL_bf, 256L*2*DIM, Gt_bf, 768L*2048, Ms3);

    // ---- quantum attention ----
    k_mgemm<2,2,2,1><<<dim3(32,36), T256, 0, stream>>>(lnx_bf, DIM, NTOK, Wqkv_bf, DIM, QKVC, DIM,
                                                       qkvb, nullptr, 0, nullptr, qkv_bf, QKVC, 1.f, 0);
    k_transv<<<dim3(8,12,NBATCH), T256, 0, stream>>>(qkv_bf, Vt_bf);
    k_mgemm_qk<2,2,2,1><<<dim3(8,8,48), T256, 0, stream>>>(qkv_bf, scores);
    k_supsoft<<<dim3(NTOK), T256, 0, stream>>>(scores, P_bf, wsup, went);
    k_cvt4<<<4096, T256, 0, stream>>>((const float4*)ndw, (ushort4*)ndw_bf, NEXP*DIM*EDIM/4);
    k_mgemm_pv<1,1,2,1><<<dim3(16,2,48), T64, 0, stream>>>(P_bf, Vt_bf, o_bf);
    k_mgemm<2,2,1,1><<<dim3(64,24), T256, 0, stream>>>(o_bf, DIM, NTOK, Wproj_bf, DIM, DIM, DIM,
                                                       projb, x, DIM, attnd, nullptr, DIM, 1.f, 0);
    // ---- MoE ----
    k_ln<<<NTOK, T256, 0, stream>>>(attnd, ln2g, ln2b, nullptr, lnx_bf);
    k_route<<<NTOK, T256, 0, stream>>>(lnx_bf, Wrout, rb, dr, did, topi, topw, cnt);
    k_prefix<<<1, 1, 0, stream>>>(cnt, prefix);
    k_assign<<<8, T256, 0, stream>>>(topi, prefix, cnt2, rowof, tokof);
    k_gather<<<dim3(1536), T256, 0, stream>>>(lnx_bf, tokof, Xg_bf);
    k_mgemm_expert<2,2,2,1><<<dim3(32,48,NEXP), T256, 0, stream>>>(Xg_bf, DIM, Wexp_bf, DIM, (long)EDIM*DIM,
                                                                   eb, EDIM, prefix, cnt,
                                                                   nullptr, hidden_bf, EDIM, EDIM, DIM, 1);
    k_mgemm_expert<2,2,1,1><<<dim3(64,24,NEXP), T256, 0, stream>>>(hidden_bf, EDIM, ndw_bf, EDIM, (long)DIM*EDIM,
                                                                   ndb, DIM, prefix, cnt,
                                                                   outg, nullptr, DIM, DIM, EDIM, 0);
    k_combine<<<dim3(6144), T256, 0, stream>>>(attnd, outg, rowof, topw, eo, inx_bf);
    // ---- fractal memory (3 levels; K/V + Gt precomputed above; 3 dispatches/level) ----
    int Ms[3] = {64, 128, 256};
    for (int l=0; l<3; ++l){
        const u16* iwl = inw_bf + (size_t)l*QKVC*DIM;
        int M = Ms[l];
        k_mgemm<2,2,1,1><<<dim3(64,24), T256, 0, stream>>>(inx_bf, DIM, NTOK, iwl, DIM, DIM, DIM,
                                                           inb + (size_t)l*QKVC, nullptr, 0, nullptr, qm_bf, DIM, 1.f, 0);
        k_memqk_soft<<<dim3(NTOK/64, MHEADS), T256, 0, stream>>>(qm_bf, kvL_bf + (size_t)l*256*2*DIM, 2*DIM,
                                                                 Pm_bf, M, 0.10206207261596577f);
        // fused PV + (out-proj ∘ proc-proj): a_l = Pcat @ Gt[l]^T + bc ; accum += a_l ; inx_bf = bf16(a_l)
        k_mgemm<2,2,1,1><<<dim3(64,24), T256, 0, stream>>>(Pm_bf, 8*M, NTOK, Gt_bf + (size_t)l*768*2048, 8*M, DIM, 8*M,
                                                           bcb + (size_t)l*DIM, (l==0 ? eo : accum), DIM,
                                                           accum, inx_bf, DIM, 1.f, 0);
    }
    k_ln<<<NTOK, T256, 0, stream>>>(accum, ln3g, ln3b, outf, nullptr);
}

// Round 16
// 594.672 us; speedup vs baseline: 1.0232x; 1.0010x over previous
//
#include <hip/hip_runtime.h>
#include <math.h>

#define DIM    768
#define NTOK   2048
#define NSEQ   512
#define NBATCH 4
#define NHEADS 12
#define HD     64
#define QKVC   2304
#define MHEADS 8
#define MHD    96
#define NEXP   8
#define EDIM   3072
#define DD     (DIM*DIM)
#define PADROWS 4608   // max padded gathered rows (4096 + 8*63, rounded up)

typedef unsigned short u16;
typedef __attribute__((ext_vector_type(8))) short short8;
typedef __attribute__((ext_vector_type(4))) float f32x4;

struct L3 { long a, b, c; };
struct I3 { int a, b, c; };
struct CJ { const float4* s[6]; ushort4* d[6]; int n4[6]; };

__device__ __forceinline__ float gelu_exact(float v){
    return 0.5f * v * (1.f + erff(v * 0.70710678118654752f));
}
__device__ __forceinline__ u16 f2bf(float f){
    unsigned int u = __builtin_bit_cast(unsigned int, f);
    unsigned int r = (u + 0x7FFFu + ((u >> 16) & 1u)) >> 16;
    return (u16)r;
}
__device__ __forceinline__ float bf2f(u16 b){
    unsigned int u = ((unsigned int)b) << 16;
    return __builtin_bit_cast(float, u);
}
__device__ __forceinline__ float fast_tanh(float s){
    return 1.f - 2.f/(__expf(2.f*s) + 1.f);
}
// async global->LDS, 16B per lane; LDS dest linear (wave-uniform base + lane*16)
__device__ __forceinline__ void gll16(const u16* g, u16* l){
    __builtin_amdgcn_global_load_lds((const __attribute__((address_space(1))) void*)g,
                                     (__attribute__((address_space(3))) void*)l, 16, 0, 0);
}

// ================= MFMA bf16 GEMM core =================
// Per-wave tile (16*FR)^2; block tile (WM*16*FR)x(WN*16*FR); BK=64; WM*WN waves.
// DB=1: double-buffered LDS (stage t+1 issued before compute t, ONE barrier/k-step).
// R9: counted-vmcnt REGRESSED. R10: FR=4 regresses latency-bound experts.
// R12/R13: FR=1 wins ONLY for wave-starved grids (<~1000 blocks). R14: FR=1 on large grids REGRESSED.
// R16: flat expert grids (aligned prefix, no dead blocks).
// XOR-swizzled LDS via pre-swizzled global SOURCE + linear global_load_lds dest (m201 rule).
template<int WM,int WN,int FR,int DB>
__device__ __forceinline__ void mgemm_core(
    const u16* __restrict__ Xb, int ldx, int rowBase, int rowLim,
    const u16* __restrict__ Wb, int ldw, int colBase, int colLim, int K,
    const float* __restrict__ bias,
    const float* __restrict__ res, int ldres,
    float* __restrict__ Cf, u16* __restrict__ Cb, int ldc,
    float scale, int act)
{
    constexpr int TM = 16*FR;
    constexpr int RM = WM*TM, RN = WN*TM, NT = WM*WN*64;
    constexpr int IA = (RM*8)/NT, IB = (RN*8)/NT;
    constexpr int NB = DB ? 2 : 1;
    __shared__ u16 As[NB][RM*64];
    __shared__ u16 Bs[NB][RN*64];
    int tid = threadIdx.x;
    int lane = tid & 63, w = tid >> 6;
    int wm = (w / WN) * TM, wn = (w % WN) * TM;
    const f32x4 zf = {0.f, 0.f, 0.f, 0.f};
    f32x4 acc[FR][FR];
    #pragma unroll
    for (int i=0;i<FR;i++)
        #pragma unroll
        for (int j=0;j<FR;j++) acc[i][j] = zf;

    const bool fullA = (rowBase + RM <= rowLim);
    const bool fullB = (colBase + RN <= colLim);
    const int nt = (K + 63) >> 6;
    int lr = lane & 15, lk = lane >> 4;

    auto stage = [&](int buf, int k0){
        const bool kfull = (k0 + 64 <= K);
        if (fullA && kfull) {
            #pragma unroll
            for (int it = 0; it < IA; ++it) {
                int idx = it*NT + tid;
                int r = idx >> 3, c = idx & 7;
                gll16(&Xb[(size_t)(rowBase + r)*ldx + k0 + ((c ^ (r & 7)) << 3)], &As[buf][(size_t)idx*8]);
            }
        } else {
            #pragma unroll
            for (int it = 0; it < IA; ++it) {
                int idx = it*NT + tid;
                int r = idx >> 3, c = idx & 7;
                int gr = rowBase + r;
                uint4 v = {0u,0u,0u,0u};
                if (gr < rowLim && (k0 + c*8) < K) v = *(const uint4*)&Xb[(size_t)gr*ldx + k0 + c*8];
                *(uint4*)&As[buf][r*64 + ((c ^ (r & 7)) * 8)] = v;
            }
        }
        if (fullB && kfull) {
            #pragma unroll
            for (int it = 0; it < IB; ++it) {
                int idx = it*NT + tid;
                int r = idx >> 3, c = idx & 7;
                gll16(&Wb[(size_t)(colBase + r)*ldw + k0 + ((c ^ (r & 7)) << 3)], &Bs[buf][(size_t)idx*8]);
            }
        } else {
            #pragma unroll
            for (int it = 0; it < IB; ++it) {
                int idx = it*NT + tid;
                int r = idx >> 3, c = idx & 7;
                int gc = colBase + r;
                uint4 v = {0u,0u,0u,0u};
                if (gc < colLim && (k0 + c*8) < K) v = *(const uint4*)&Wb[(size_t)gc*ldw + k0 + c*8];
                *(uint4*)&Bs[buf][r*64 + ((c ^ (r & 7)) * 8)] = v;
            }
        }
    };
    auto compute = [&](const u16* Ac, const u16* Bc){
        #pragma unroll
        for (int ks = 0; ks < 2; ++ks) {
            short8 af[FR], bfr[FR];
            #pragma unroll
            for (int mi=0; mi<FR; mi++){
                int row = wm + mi*16 + lr;
                int cidx = (ks*4 + lk) ^ (row & 7);
                af[mi] = *(const short8*)&Ac[row*64 + cidx*8];
            }
            #pragma unroll
            for (int ni=0; ni<FR; ni++){
                int col = wn + ni*16 + lr;
                int cidx = (ks*4 + lk) ^ (col & 7);
                bfr[ni] = *(const short8*)&Bc[col*64 + cidx*8];
            }
            #pragma unroll
            for (int mi=0; mi<FR; mi++)
                #pragma unroll
                for (int ni=0; ni<FR; ni++)
                    acc[mi][ni] = __builtin_amdgcn_mfma_f32_16x16x32_bf16(af[mi], bfr[ni], acc[mi][ni], 0, 0, 0);
        }
    };

    if (DB) {
        stage(0, 0);
        __syncthreads();
        for (int t = 0; t < nt; ++t) {
            if (t + 1 < nt) stage((t+1)&1, (t+1)*64);
            compute(As[t&1], Bs[t&1]);
            __syncthreads();
        }
    } else {
        for (int t = 0; t < nt; ++t) {
            stage(0, t*64);
            __syncthreads();
            compute(As[0], Bs[0]);
            __syncthreads();
        }
    }
    // epilogue: D row = (lane>>4)*4 + reg, col = lane&15  [m89-verified]
    int lg = lane >> 4;
    #pragma unroll
    for (int mi=0; mi<FR; mi++){
        #pragma unroll
        for (int r=0; r<4; r++){
            int row = rowBase + wm + mi*16 + lg*4 + r;
            if (row >= rowLim) continue;
            #pragma unroll
            for (int ni=0; ni<FR; ni++){
                int col = colBase + wn + ni*16 + lr;
                if (col >= colLim) continue;
                float v = acc[mi][ni][r] * scale;
                if (bias) v += bias[col];
                if (act == 1) v = gelu_exact(v);
                if (Cb) Cb[(size_t)row*ldc + col] = f2bf(v);
                if (res) v += res[(size_t)row*ldres + col];
                if (Cf) Cf[(size_t)row*ldc + col] = v;
            }
        }
    }
}

template<int WM,int WN,int FR,int DB>
__global__ __launch_bounds__(WM*WN*64) void k_mgemm(
    const u16* __restrict__ X, int ldx, int M,
    const u16* __restrict__ W, int ldw, int N, int K,
    const float* __restrict__ bias, const float* __restrict__ res, int ldres,
    float* __restrict__ Cf, u16* __restrict__ Cb, int ldc, float scale, int act)
{
    constexpr int RM = WM*16*FR, RN = WN*16*FR;
    mgemm_core<WM,WN,FR,DB>(X, ldx, blockIdx.x*RM, M, W, ldw, blockIdx.y*RN, N, K,
                            bias, res, ldres, Cf, Cb, ldc, scale, act);
}

// batched-by-3 variant: z selects offsets into X/W/bias/C and M
template<int WM,int WN,int FR,int DB>
__global__ __launch_bounds__(WM*WN*64) void k_mgemm_b3(
    const u16* __restrict__ X, L3 xo, int ldx, I3 Mv,
    const u16* __restrict__ W, L3 wo, int ldw, int N, int K,
    const float* __restrict__ bias, L3 bo,
    u16* __restrict__ Cb, L3 co, int ldc, float scale, int act)
{
    constexpr int RM = WM*16*FR, RN = WN*16*FR;
    int z = blockIdx.z;
    int M    = (z==0) ? Mv.a : (z==1) ? Mv.b : Mv.c;
    long xof = (z==0) ? xo.a : (z==1) ? xo.b : xo.c;
    long wof = (z==0) ? wo.a : (z==1) ? wo.b : wo.c;
    long bof = (z==0) ? bo.a : (z==1) ? bo.b : bo.c;
    long cof = (z==0) ? co.a : (z==1) ? co.b : co.c;
    if ((int)blockIdx.x * RM >= M) return;
    mgemm_core<WM,WN,FR,DB>(X + xof, ldx, blockIdx.x*RM, M, W + wof, ldw, blockIdx.y*RN, N, K,
                            bias ? bias + bof : nullptr, nullptr, 0, nullptr, Cb + cof, ldc, scale, act);
}

// ===== flat expert GEMM: prefix[] is 64-aligned cumsum (9 entries, prefix[8]=padded total) =====
// Every launched block maps to exactly one expert row-tile (no dead z-blocks).
template<int WM,int WN,int FR,int DB>
__global__ __launch_bounds__(WM*WN*64) void k_mgemm_expert_flat(
    const u16* __restrict__ X, int ldx,
    const u16* __restrict__ Wb, int ldw, long wStride,
    const float* __restrict__ biasB, int biasStride,
    const int* __restrict__ prefix, const int* __restrict__ cnt,
    float* __restrict__ Cf, u16* __restrict__ Cb, int ldc, int N, int K, int act)
{
    constexpr int RM = WM*16*FR, RN = WN*16*FR;
    int rowBase = (int)blockIdx.x * RM;
    if (rowBase >= prefix[8]) return;
    int e = 0;
    #pragma unroll
    for (int i=0;i<7;i++) if (rowBase >= prefix[i+1]) e = i+1;
    int rowLim = prefix[e] + cnt[e];
    if (rowBase >= rowLim) return;   // tile fully inside pad region
    mgemm_core<WM,WN,FR,DB>(X, ldx, rowBase, rowLim,
                            Wb + (size_t)e*wStride, ldw, blockIdx.y*RN, N, K,
                            biasB + (size_t)e*biasStride, nullptr, 0, Cf, Cb, ldc, 1.f, act);
}

// scores[b,h,n,m] = 0.125 * q_n . k_m  (bf16 out)
template<int WM,int WN,int FR,int DB>
__global__ __launch_bounds__(WM*WN*64) void k_mgemm_qk(const u16* __restrict__ qkv, u16* __restrict__ attn)
{
    constexpr int RM = WM*16*FR, RN = WN*16*FR;
    int z = blockIdx.z, b = z / NHEADS, h = z % NHEADS;
    const u16* X = qkv + (size_t)b*NSEQ*QKVC + h*HD;          // q
    const u16* W = qkv + (size_t)b*NSEQ*QKVC + DIM + h*HD;    // k
    u16* C = attn + (size_t)z*NSEQ*NSEQ;
    mgemm_core<WM,WN,FR,DB>(X, QKVC, blockIdx.x*RM, NSEQ, W, QKVC, blockIdx.y*RN, NSEQ, HD,
                            nullptr, nullptr, 0, nullptr, C, NSEQ, 0.125f, 0);
}

// o[b,n,h*64+d] = sum_m P[b,h,n,m] * V[b,m,h*64+d]; Vt[b][d][m] supplies W
template<int WM,int WN,int FR,int DB>
__global__ __launch_bounds__(WM*WN*64) void k_mgemm_pv(const u16* __restrict__ P, const u16* __restrict__ Vt, u16* __restrict__ o)
{
    constexpr int RM = WM*16*FR, RN = WN*16*FR;
    int z = blockIdx.z, b = z / NHEADS, h = z % NHEADS;
    const u16* X = P + (size_t)z*NSEQ*NSEQ;
    const u16* W = Vt + ((size_t)b*DIM + h*HD)*NSEQ;
    u16* C = o + (size_t)b*NSEQ*DIM + h*HD;
    mgemm_core<WM,WN,FR,DB>(X, NSEQ, blockIdx.x*RM, NSEQ, W, NSEQ, blockIdx.y*RN, HD, NSEQ,
                            nullptr, nullptr, 0, nullptr, C, DIM, 1.f, 0);
}

// ===== Gt build: Gt[l][j][h*M+m] = sum_d Wc[l][j][h*96+d] * V[l][m][h*96+d] =====
template<int WM,int WN,int FR,int DB>
__global__ __launch_bounds__(WM*WN*64) void k_gt(
    const u16* __restrict__ Wc, const u16* __restrict__ kvL, long kvStride,
    u16* __restrict__ Gt, long gtStride, I3 Mv)
{
    constexpr int RM = WM*16*FR, RN = WN*16*FR;
    int z = blockIdx.z, l = z >> 3, h = z & 7;
    int M = (l==0) ? Mv.a : (l==1) ? Mv.b : Mv.c;
    if ((int)blockIdx.y * RN >= M) return;
    mgemm_core<WM,WN,FR,DB>(Wc + (size_t)l*DD + h*MHD, DIM, blockIdx.x*RM, DIM,
                            kvL + (size_t)l*kvStride + DIM + h*MHD, 2*DIM, blockIdx.y*RN, M, MHD,
                            nullptr, nullptr, 0, nullptr,
                            Gt + (size_t)l*gtStride + (size_t)h*M, 8*M, 1.f, 0);
}

// ===== fused mem-MHA scores + row softmax: block = 64 q-rows x full M (<=256), 4 waves =====
// writes P[n][h*M+m] (token-major) so the PV+proj GEMM consumes it as one (2048 x 8M) operand
__global__ __launch_bounds__(256) void k_memqk_soft(
    const u16* __restrict__ q, const u16* __restrict__ kv, int ldk,
    u16* __restrict__ P, int M, float scale)
{
    constexpr int RM = 64, RN = 256, NT = 256, K = MHD;
    __shared__ u16 As[RM*64];
    __shared__ u16 Bs[RN*64];
    __shared__ float red0[RM][4];
    __shared__ float red1[RM][4];
    int h = blockIdx.y;
    int rowBase = blockIdx.x * RM;
    const u16* Xb = q + h*MHD;     // ldx = DIM
    const u16* Wb = kv + h*MHD;    // ldw = ldk
    int tid = threadIdx.x, lane = tid & 63, w = tid >> 6;
    int wn = w * 64;
    int lr = lane & 15, lk = lane >> 4;
    const f32x4 zf = {0.f,0.f,0.f,0.f};
    f32x4 acc[4][4];
    #pragma unroll
    for (int i=0;i<4;i++)
        #pragma unroll
        for (int j=0;j<4;j++) acc[i][j] = zf;

    for (int k0 = 0; k0 < K; k0 += 64) {
        const bool kfull = (k0 + 64 <= K);
        if (kfull) {
            #pragma unroll
            for (int it = 0; it < 2; ++it) {
                int idx = it*NT + tid;
                int r = idx >> 3, c = idx & 7;
                gll16(&Xb[(size_t)(rowBase + r)*DIM + k0 + ((c ^ (r & 7)) << 3)], &As[(size_t)idx*8]);
            }
        } else {
            #pragma unroll
            for (int it = 0; it < 2; ++it) {
                int idx = it*NT + tid;
                int r = idx >> 3, c = idx & 7;
                uint4 v = {0u,0u,0u,0u};
                if ((k0 + c*8) < K) v = *(const uint4*)&Xb[(size_t)(rowBase + r)*DIM + k0 + c*8];
                *(uint4*)&As[r*64 + ((c ^ (r & 7)) * 8)] = v;
            }
        }
        #pragma unroll
        for (int it = 0; it < 8; ++it) {
            int idx = it*NT + tid;
            int r = idx >> 3, c = idx & 7;
            uint4 v = {0u,0u,0u,0u};
            if (r < M && (k0 + c*8) < K) v = *(const uint4*)&Wb[(size_t)r*ldk + k0 + c*8];
            *(uint4*)&Bs[r*64 + ((c ^ (r & 7)) * 8)] = v;
        }
        __syncthreads();
        #pragma unroll
        for (int ks = 0; ks < 2; ++ks) {
            short8 af[4], bfr[4];
            #pragma unroll
            for (int mi=0; mi<4; mi++){
                int row = mi*16 + lr;
                int cidx = (ks*4 + lk) ^ (row & 7);
                af[mi] = *(const short8*)&As[row*64 + cidx*8];
            }
            #pragma unroll
            for (int ni=0; ni<4; ni++){
                int col = wn + ni*16 + lr;
                int cidx = (ks*4 + lk) ^ (col & 7);
                bfr[ni] = *(const short8*)&Bs[col*64 + cidx*8];
            }
            #pragma unroll
            for (int mi=0; mi<4; mi++)
                #pragma unroll
                for (int ni=0; ni<4; ni++)
                    acc[mi][ni] = __builtin_amdgcn_mfma_f32_16x16x32_bf16(af[mi], bfr[ni], acc[mi][ni], 0, 0, 0);
        }
        __syncthreads();
    }
    int lg = lane >> 4;
    float sc[4][4][4];
    float rmax[4][4];
    #pragma unroll
    for (int mi=0; mi<4; mi++){
        #pragma unroll
        for (int r=0; r<4; r++){
            float m = -1e30f;
            #pragma unroll
            for (int ni=0; ni<4; ni++){
                int col = wn + ni*16 + lr;
                float v = (col < M) ? acc[mi][ni][r]*scale : -1e30f;
                sc[mi][r][ni] = v;
                m = fmaxf(m, v);
            }
            m = fmaxf(m, __shfl_xor(m, 1));
            m = fmaxf(m, __shfl_xor(m, 2));
            m = fmaxf(m, __shfl_xor(m, 4));
            m = fmaxf(m, __shfl_xor(m, 8));
            rmax[mi][r] = m;
        }
    }
    if (lr == 0){
        #pragma unroll
        for (int mi=0; mi<4; mi++)
            #pragma unroll
            for (int r=0; r<4; r++) red0[mi*16 + lg*4 + r][w] = rmax[mi][r];
    }
    __syncthreads();
    float gmax[4][4], rsum[4][4];
    #pragma unroll
    for (int mi=0; mi<4; mi++){
        #pragma unroll
        for (int r=0; r<4; r++){
            int row = mi*16 + lg*4 + r;
            float g = fmaxf(fmaxf(red0[row][0], red0[row][1]), fmaxf(red0[row][2], red0[row][3]));
            gmax[mi][r] = g;
            float s = 0.f;
            #pragma unroll
            for (int ni=0; ni<4; ni++){
                int col = wn + ni*16 + lr;
                if (col < M) s += __expf(sc[mi][r][ni] - g);
            }
            s += __shfl_xor(s, 1);
            s += __shfl_xor(s, 2);
            s += __shfl_xor(s, 4);
            s += __shfl_xor(s, 8);
            rsum[mi][r] = s;
        }
    }
    if (lr == 0){
        #pragma unroll
        for (int mi=0; mi<4; mi++)
            #pragma unroll
            for (int r=0; r<4; r++) red1[mi*16 + lg*4 + r][w] = rsum[mi][r];
    }
    __syncthreads();
    #pragma unroll
    for (int mi=0; mi<4; mi++){
        #pragma unroll
        for (int r=0; r<4; r++){
            int row = mi*16 + lg*4 + r;
            float tot = red1[row][0] + red1[row][1] + red1[row][2] + red1[row][3];
            float inv = 1.f / tot;
            #pragma unroll
            for (int ni=0; ni<4; ni++){
                int col = wn + ni*16 + lr;
                if (col < M)
                    P[(((size_t)(rowBase + row))*MHEADS + h)*M + col] = f2bf(__expf(sc[mi][r][ni] - gmax[mi][r]) * inv);
            }
        }
    }
}

// batched outw transpose: wT3[z][c][r] = outw[z][r][c]
__global__ __launch_bounds__(256) void k_transw_b(const u16* __restrict__ src, u16* __restrict__ dst)
{
    int z = blockIdx.y;
    int idx = blockIdx.x*256 + threadIdx.x;
    int r = idx / DIM, c = idx % DIM;
    dst[(size_t)z*DD + (size_t)c*DIM + r] = src[(size_t)z*DD + (size_t)r*DIM + c];
}

// ================= PHM weight materialization, 4-wide (Si divisible by 4) =================
__global__ __launch_bounds__(256) void k_phm4(
    const float* __restrict__ A, const float* __restrict__ S, void* __restrict__ W,
    int So, int Si, int inF, long Astride, long Sstride, long Wstride, int obf)
{
    int e = blockIdx.y;
    const float* Ae = A + (size_t)e*Astride;
    const float* Se = S + (size_t)e*Sstride;
    size_t idx = (size_t)blockIdx.x*256 + threadIdx.x;
    int inF4 = inF >> 2;
    size_t total = (size_t)(So*4) * inF4;
    if (idx >= total) return;
    int in4 = (int)(idx % inF4);
    int o   = (int)(idx / inF4);
    int a = o / So, c = o % So;
    int in0 = in4 * 4;
    int b = in0 / Si, d = in0 % Si;
    float4 acc = {0.f,0.f,0.f,0.f};
    #pragma unroll
    for (int i=0;i<4;i++){
        float av = Ae[i*16 + a*4 + b];
        float4 sv = *(const float4*)&Se[((size_t)i*So + c)*Si + d];
        acc.x = fmaf(av, sv.x, acc.x);
        acc.y = fmaf(av, sv.y, acc.y);
        acc.z = fmaf(av, sv.z, acc.z);
        acc.w = fmaf(av, sv.w, acc.w);
    }
    size_t oidx = (size_t)o*inF + in0;
    if (obf){
        ushort4 r; r.x=f2bf(acc.x); r.y=f2bf(acc.y); r.z=f2bf(acc.z); r.w=f2bf(acc.w);
        *(ushort4*)&((u16*)W)[(size_t)e*Wstride + oidx] = r;
    } else {
        *(float4*)&((float*)W)[(size_t)e*Wstride + oidx] = acc;
    }
}

// ================= fp32 -> bf16 converts =================
__global__ __launch_bounds__(256) void k_cvt4(const float4* __restrict__ s, ushort4* __restrict__ d, int n4)
{
    for (int i = blockIdx.x*256 + threadIdx.x; i < n4; i += gridDim.x*256){
        float4 v = s[i];
        ushort4 o; o.x = f2bf(v.x); o.y = f2bf(v.y); o.z = f2bf(v.z); o.w = f2bf(v.w);
        d[i] = o;
    }
}
__global__ __launch_bounds__(256) void k_cvt_multi(CJ J)
{
    int z = blockIdx.y;
    const float4* s = J.s[z]; ushort4* d = J.d[z]; int n4 = J.n4[z];
    for (int i = blockIdx.x*256 + threadIdx.x; i < n4; i += gridDim.x*256){
        float4 v = s[i];
        ushort4 o; o.x = f2bf(v.x); o.y = f2bf(v.y); o.z = f2bf(v.z); o.w = f2bf(v.w);
        d[i] = o;
    }
}

// bc[l][i] = dot(pw[l][i][:], outb[l][:]) + pb[l][i]
__global__ __launch_bounds__(256) void k_bc(const float* __restrict__ pw, const float* __restrict__ outb,
                                            const float* __restrict__ pb, float* __restrict__ bc)
{
    int l = blockIdx.y;
    int i = blockIdx.x*4 + (threadIdx.x >> 6);
    int lane = threadIdx.x & 63;
    const float* pr = pw + ((size_t)l*DIM + i)*DIM;
    const float* ob = outb + (size_t)l*DIM;
    float s = 0.f;
    for (int j = lane; j < DIM; j += 64) s = fmaf(pr[j], ob[j], s);
    for (int off=32; off; off>>=1) s += __shfl_xor(s, off);
    if (lane == 0) bc[(size_t)l*DIM + i] = s + pb[(size_t)l*DIM + i];
}

// ================= LayerNorm (row=768), dual output =================
__global__ __launch_bounds__(256) void k_ln(const float* __restrict__ x, const float* __restrict__ g,
                                            const float* __restrict__ b,
                                            float* __restrict__ yf, u16* __restrict__ yb)
{
    int row = blockIdx.x, tid = threadIdx.x;
    const float* xr = x + (size_t)row * DIM;
    float v0 = xr[tid], v1 = xr[tid+256], v2 = xr[tid+512];
    float s = v0+v1+v2;
    float ss = v0*v0 + v1*v1 + v2*v2;
    for (int off=32; off; off>>=1){ s += __shfl_xor(s,off); ss += __shfl_xor(ss,off); }
    __shared__ float sa[4], sb[4];
    int wid = tid >> 6;
    if ((tid & 63) == 0){ sa[wid]=s; sb[wid]=ss; }
    __syncthreads();
    s  = sa[0]+sa[1]+sa[2]+sa[3];
    ss = sb[0]+sb[1]+sb[2]+sb[3];
    float mean = s * (1.f/DIM);
    float var  = ss * (1.f/DIM) - mean*mean;
    float rstd = rsqrtf(var + 1e-5f);
    float o0 = (v0-mean)*rstd*g[tid]     + b[tid];
    float o1 = (v1-mean)*rstd*g[tid+256] + b[tid+256];
    float o2 = (v2-mean)*rstd*g[tid+512] + b[tid+512];
    if (yf){ float* yr = yf + (size_t)row*DIM; yr[tid]=o0; yr[tid+256]=o1; yr[tid+512]=o2; }
    if (yb){ u16* yr = yb + (size_t)row*DIM; yr[tid]=f2bf(o0); yr[tid+256]=f2bf(o1); yr[tid+512]=f2bf(o2); }
}

// ===== fused sup/ent mix + tanh + softmax (bf16 scores in, uint4 loads): block per (b,n) =====
__global__ __launch_bounds__(256) void k_supsoft(
    const u16* __restrict__ attn, u16* __restrict__ P,
    const float* __restrict__ wsup, const float* __restrict__ went)
{
    __shared__ float S[NHEADS][NSEQ];
    __shared__ float ws[144], we[144];
    int bn = blockIdx.x;
    int b = bn >> 9, n = bn & 511;
    int tid = threadIdx.x;
    if (tid < 144){ ws[tid] = wsup[tid]; we[tid] = went[tid]; }
    size_t base = ((size_t)b*NHEADS*NSEQ + n)*NSEQ;
    #pragma unroll
    for (int it=0; it<3; ++it){
        int idx = it*256 + tid;
        int j = idx >> 6, m8 = (idx & 63) * 8;
        uint4 v = *(const uint4*)&attn[base + (size_t)j*NSEQ*NSEQ + m8];
        S[j][m8+0] = bf2f((u16)(v.x & 0xFFFFu)); S[j][m8+1] = bf2f((u16)(v.x >> 16));
        S[j][m8+2] = bf2f((u16)(v.y & 0xFFFFu)); S[j][m8+3] = bf2f((u16)(v.y >> 16));
        S[j][m8+4] = bf2f((u16)(v.z & 0xFFFFu)); S[j][m8+5] = bf2f((u16)(v.z >> 16));
        S[j][m8+6] = bf2f((u16)(v.w & 0xFFFFu)); S[j][m8+7] = bf2f((u16)(v.w >> 16));
    }
    __syncthreads();
    #pragma unroll
    for (int half=0; half<2; ++half){
        int m = tid + half*256;
        float av[12], sup[12];
        #pragma unroll
        for (int j=0;j<12;j++) av[j] = S[j][m];
        #pragma unroll
        for (int i=0;i<12;i++){
            float s = 0.f;
            #pragma unroll
            for (int j=0;j<12;j++) s = fmaf(ws[i*12+j], av[j], s);
            sup[i] = s;
        }
        #pragma unroll
        for (int i=0;i<12;i++){
            float s = sup[i];
            #pragma unroll
            for (int j=0;j<12;j++) s = fmaf(we[i*12+j], sup[j], s);
            av[i] = fast_tanh(s);
        }
        #pragma unroll
        for (int i=0;i<12;i++) S[i][m] = av[i];
    }
    __syncthreads();
    int lane = tid & 63, wv = tid >> 6;
    #pragma unroll
    for (int jj=0; jj<3; ++jj){
        int j = wv*3 + jj;
        float v[8], mx = -1e30f;
        #pragma unroll
        for (int k=0;k<8;k++){ v[k] = S[j][lane + 64*k]; mx = fmaxf(mx, v[k]); }
        for (int off=32; off; off>>=1) mx = fmaxf(mx, __shfl_xor(mx, off));
        float sum = 0.f;
        #pragma unroll
        for (int k=0;k<8;k++){ v[k] = __expf(v[k]-mx); sum += v[k]; }
        for (int off=32; off; off>>=1) sum += __shfl_xor(sum, off);
        float inv = 1.f/sum;
        #pragma unroll
        for (int k=0;k<8;k++) P[base + (size_t)j*NSEQ*NSEQ + lane + 64*k] = f2bf(v[k]*inv);
    }
}

// ================= V transpose (main attn): Vt[b][d][m] = qkv_bf[b][m][1536+d] =================
__global__ __launch_bounds__(256) void k_transv(const u16* __restrict__ qkv, u16* __restrict__ Vt)
{
    __shared__ u16 L[64][65];
    int mt = blockIdx.x*64, dt = blockIdx.y*64, b = blockIdx.z;
    int tid = threadIdx.x;
    #pragma unroll
    for (int it=0; it<16; ++it){
        int idx = it*256 + tid;
        int mm = idx >> 6, dd = idx & 63;
        L[mm][dd] = qkv[((size_t)b*NSEQ + mt + mm)*QKVC + 1536 + dt + dd];
    }
    __syncthreads();
    #pragma unroll
    for (int it=0; it<16; ++it){
        int idx = it*256 + tid;
        int dd = idx >> 6, mm = idx & 63;
        Vt[((size_t)b*DIM + dt + dd)*NSEQ + mt + mm] = L[mm][dd];
    }
}

// ================= MoE routing (bf16 input) =================
__global__ __launch_bounds__(256) void k_route(
    const u16* __restrict__ ln2, const float* __restrict__ Wr,
    const float* __restrict__ rb, const float* __restrict__ dr,
    const int* __restrict__ did, int* __restrict__ topi, float* __restrict__ topw, int* __restrict__ cnt)
{
    int t = blockIdx.x, tid = threadIdx.x;
    const u16* xr = ln2 + (size_t)t*DIM;
    float a[8] = {};
    #pragma unroll
    for (int ii=0; ii<3; ii++){
        int i = tid + ii*256;
        float xv = bf2f(xr[i]);
        #pragma unroll
        for (int e=0;e<8;e++) a[e] = fmaf(xv, Wr[e*DIM + i], a[e]);
    }
    #pragma unroll
    for (int e=0;e<8;e++)
        for (int off=32; off; off>>=1) a[e] += __shfl_xor(a[e], off);
    __shared__ float sred[4][8];
    int wid = tid >> 6;
    if ((tid & 63) == 0){
        #pragma unroll
        for (int e=0;e<8;e++) sred[wid][e] = a[e];
    }
    __syncthreads();
    if (tid == 0){
        int d = did[0];
        float lg[8];
        #pragma unroll
        for (int e=0;e<8;e++) lg[e] = sred[0][e]+sred[1][e]+sred[2][e]+sred[3][e] + rb[e] + dr[d*8+e];
        int i1 = 0; float v1 = lg[0];
        #pragma unroll
        for (int e=1;e<8;e++) if (lg[e] > v1){ v1 = lg[e]; i1 = e; }
        int i2 = -1; float v2 = -1e30f;
        #pragma unroll
        for (int e=0;e<8;e++) if (e != i1 && lg[e] > v2){ v2 = lg[e]; i2 = e; }
        float e2 = __expf(v2 - v1);
        float inv = 1.f / (1.f + e2);
        topi[2*t] = i1; topi[2*t+1] = i2;
        topw[2*t] = inv; topw[2*t+1] = e2 * inv;
        atomicAdd(&cnt[i1], 1); atomicAdd(&cnt[i2], 1);
    }
}

__global__ void k_zero(int* p, int n){ int i = blockIdx.x*256 + threadIdx.x; if (i < n) p[i] = 0; }

// aligned prefix: prefix[e] = cumsum of ceil(cnt/64)*64 ; prefix[8] = padded total
__global__ void k_prefix(const int* __restrict__ cnt, int* __restrict__ prefix){
    if (threadIdx.x == 0){
        int s = 0;
        for (int e=0;e<8;e++){ prefix[e] = s; s += (cnt[e] + 63) & ~63; }
        prefix[8] = s;
    }
}

__global__ __launch_bounds__(256) void k_assign(
    const int* __restrict__ topi, const int* __restrict__ prefix,
    int* __restrict__ cnt2, int* __restrict__ rowof, int* __restrict__ tokof)
{
    int t = blockIdx.x*256 + threadIdx.x;
    if (t >= NTOK) return;
    #pragma unroll
    for (int k=0;k<2;k++){
        int e = topi[2*t+k];
        int slot = atomicAdd(&cnt2[e], 1);
        int row = prefix[e] + slot;
        rowof[2*t+k] = row;
        tokof[row] = t;
    }
}

// 16B-vectorized gather over PADROWS rows (pad rows read token 0 via zeroed tokof)
__global__ __launch_bounds__(256) void k_gather(const u16* __restrict__ src, const int* __restrict__ tokof, u16* __restrict__ dst)
{
    int i = blockIdx.x*256 + threadIdx.x;
    int row = i / 96, c = (i % 96) * 8;
    *(uint4*)&dst[(size_t)row*DIM + c] = *(const uint4*)&src[(size_t)tokof[row]*DIM + c];
}

__global__ __launch_bounds__(256) void k_combine(
    const float* __restrict__ att, const float* __restrict__ outg,
    const int* __restrict__ rowof, const float* __restrict__ topw,
    float* __restrict__ eo, u16* __restrict__ eob)
{
    size_t i = (size_t)blockIdx.x*256 + threadIdx.x;
    int t = (int)(i / DIM), c = (int)(i % DIM);
    int r0 = rowof[2*t], r1 = rowof[2*t+1];
    float v = att[i] + topw[2*t]*outg[(size_t)r0*DIM+c] + topw[2*t+1]*outg[(size_t)r1*DIM+c];
    eo[i] = v;
    eob[i] = f2bf(v);
}

// ================= host =================
extern "C" void kernel_launch(void* const* d_in, const int* in_sizes, int n_in,
                              void* d_out, int out_size, void* d_ws, size_t ws_size,
                              hipStream_t stream)
{
    const float* x     = (const float*)d_in[0];
    const float* ln1g  = (const float*)d_in[1];
    const float* ln1b  = (const float*)d_in[2];
    const float* ln2g  = (const float*)d_in[3];
    const float* ln2b  = (const float*)d_in[4];
    const float* ln3g  = (const float*)d_in[5];
    const float* ln3b  = (const float*)d_in[6];
    const float* qkvA  = (const float*)d_in[7];
    const float* qkvS  = (const float*)d_in[8];
    const float* qkvb  = (const float*)d_in[9];
    const float* projA = (const float*)d_in[10];
    const float* projS = (const float*)d_in[11];
    const float* projb = (const float*)d_in[12];
    const float* wsup  = (const float*)d_in[13];
    const float* went  = (const float*)d_in[14];
    const float* rA    = (const float*)d_in[15];
    const float* rS    = (const float*)d_in[16];
    const float* rb    = (const float*)d_in[17];
    const float* dr    = (const float*)d_in[18];
    const float* eA    = (const float*)d_in[19];
    const float* eS    = (const float*)d_in[20];
    const float* eb    = (const float*)d_in[21];
    const float* ndw   = (const float*)d_in[22];
    const float* ndb   = (const float*)d_in[23];
    const float* mem0  = (const float*)d_in[24];
    const float* mem1  = (const float*)d_in[25];
    const float* mem2  = (const float*)d_in[26];
    const float* inw   = (const float*)d_in[27];
    const float* inb   = (const float*)d_in[28];
    const float* outw  = (const float*)d_in[29];
    const float* outb  = (const float*)d_in[30];
    const float* pw    = (const float*)d_in[31];
    const float* pb    = (const float*)d_in[32];
    const int*   did   = (const int*)d_in[33];

    float* f = (float*)d_ws;
    size_t off = 0;
    auto alloc = [&](size_t n){ float* p = f + off; off += (n + 3) & ~(size_t)3; return p; };
    auto allocb = [&](size_t n){ return (u16*)alloc((n + 1) / 2); };

    // fp32 buffers
    float* attnd  = alloc((size_t)NTOK*DIM);
    float* eo     = alloc((size_t)NTOK*DIM);
    float* accum  = alloc((size_t)NTOK*DIM);
    float* attnb  = alloc((size_t)48*NSEQ*NSEQ);   // u16 scores; hosts outg + ndw_bf
    float* Wrout  = alloc((size_t)NEXP*DIM);
    float* topw   = alloc((size_t)2*NTOK);
    float* bcb    = alloc((size_t)3*DIM);
    int* ip = (int*)alloc((size_t)4*NTOK + PADROWS + 64);
    int* topi   = ip;            ip += 2*NTOK;
    int* rowof  = ip;            ip += 2*NTOK;
    int* tokof  = ip;            ip += PADROWS;
    int* cnt    = ip;            ip += 8;
    int* cnt2   = ip;            ip += 8;
    int* prefix = ip;            ip += 16;

    // aliases inside attnb (scores dead after supsoft); outg sized for PADROWS
    u16*   scores = (u16*)attnb;                         // 48*512*512 u16
    float* outg   = attnb;                               // PADROWS x 768 fp32 (MoE)
    u16*   ndw_bf = (u16*)(attnb + (size_t)3538944);     // after PADROWS*768 floats; 18.87M u16 fits (12.58M-3.54M)*2=18.1M.. see note
    // NOTE: ndw needs 18.87M u16 = 9.44M floats; attnb has 12.58M floats; 3.54M + 9.44M = 12.98M > 12.58M -> move ndw to own buffer below.

    // bf16 buffers
    u16* Wqkv_bf  = allocb((size_t)QKVC*DIM);
    u16* Wproj_bf = allocb((size_t)DD);
    u16* Wexp_bf  = allocb((size_t)NEXP*EDIM*DIM);
    u16* ndw_bf2  = allocb((size_t)NEXP*DIM*EDIM);  // dedicated (alias math got tight with PADROWS)
    u16* inw_bf   = allocb((size_t)3*QKVC*DIM);
    u16* outw_bf  = allocb((size_t)3*DD);
    u16* pw_bf    = allocb((size_t)3*DD);
    u16* Wc_bf    = allocb((size_t)3*DD);
    u16* wT3_bf   = allocb((size_t)3*DD);
    u16* mem_bf   = allocb((size_t)448*DIM);
    u16* qkv_bf   = allocb((size_t)NTOK*QKVC);
    u16* Vt_bf    = allocb((size_t)NBATCH*DIM*NSEQ);
    u16* P_bf     = allocb((size_t)PADROWS*EDIM);   // attn P (12.58M) and hidden (PADROWS*3072=14.16M): take max
    u16* lnx_bf   = allocb((size_t)NTOK*DIM);
    u16* o_bf     = allocb((size_t)NTOK*DIM);
    u16* inx_bf   = allocb((size_t)NTOK*DIM);
    u16* Xg_bf    = allocb((size_t)PADROWS*DIM);
    u16* kvL_bf   = allocb((size_t)3*256*2*DIM);
    u16* Gt_bf    = allocb((size_t)3*768*2048);
    u16* hidden_bf= P_bf;
    u16* Pm_bf    = P_bf;
    u16* qm_bf    = o_bf;

    float* outf = (float*)d_out;
    dim3 T256(256), T64(64);
    I3 Ms3 = {64, 128, 256};

    k_zero<<<1, 32, 0, stream>>>(cnt, 16);
    k_zero<<<(PADROWS+255)/256, T256, 0, stream>>>(tokof, PADROWS);
    k_ln<<<NTOK, T256, 0, stream>>>(x, ln1g, ln1b, nullptr, lnx_bf);
    // PHM weight builds (bf16 except router), 4-wide
    k_phm4<<<dim3(1728,1), T256, 0, stream>>>(qkvA, qkvS, Wqkv_bf, 576, 192, DIM, 0,0,0, 1);
    k_phm4<<<dim3(576,1),  T256, 0, stream>>>(projA, projS, Wproj_bf, 192, 192, DIM, 0,0,0, 1);
    k_phm4<<<dim3(6,1),    T256, 0, stream>>>(rA, rS, Wrout, 2, 192, DIM, 0,0,0, 0);
    k_phm4<<<dim3(2304,NEXP), T256, 0, stream>>>(eA, eS, Wexp_bf, 768, 192, DIM,
                                                 64L, (long)4*768*192, (long)EDIM*DIM, 1);
    // all small weight converts in ONE dispatch
    {
        CJ J;
        J.s[0]=(const float4*)inw;  J.d[0]=(ushort4*)inw_bf;  J.n4[0]=3*QKVC*DIM/4;
        J.s[1]=(const float4*)outw; J.d[1]=(ushort4*)outw_bf; J.n4[1]=3*DD/4;
        J.s[2]=(const float4*)pw;   J.d[2]=(ushort4*)pw_bf;   J.n4[2]=3*DD/4;
        J.s[3]=(const float4*)mem0; J.d[3]=(ushort4*)mem_bf;              J.n4[3]=64*DIM/4;
        J.s[4]=(const float4*)mem1; J.d[4]=(ushort4*)(mem_bf + 64*DIM);   J.n4[4]=128*DIM/4;
        J.s[5]=(const float4*)mem2; J.d[5]=(ushort4*)(mem_bf + 192*DIM);  J.n4[5]=256*DIM/4;
        k_cvt_multi<<<dim3(1024, 6), T256, 0, stream>>>(J);
    }
    // fused fractal out-proj weights: Wc[l] = pw[l] @ outw[l]; bc[l] = pw[l]@outb[l] + pb[l]
    k_bc<<<dim3(DIM/4, 3), T256, 0, stream>>>(pw, outb, pb, bcb);
    k_transw_b<<<dim3(DD/256, 3), T256, 0, stream>>>(outw_bf, wT3_bf);
    {
        L3 dd3 = {0, DD, 2*DD}, z3 = {0,0,0};
        I3 m768 = {DIM, DIM, DIM};
        k_mgemm_b3<2,2,2,1><<<dim3(12,12,3), T256, 0, stream>>>(pw_bf, dd3, DIM, m768,
                                                                wT3_bf, dd3, DIM, DIM, DIM,
                                                                nullptr, z3, Wc_bf, dd3, DIM, 1.f, 0);
    }
    // all 3 fractal K|V projections (mem-side, chain-independent) in ONE dispatch
    {
        L3 xo = {0, 64L*DIM, 192L*DIM};
        L3 wo = {(long)DD, (long)QKVC*DIM + DD, 2L*QKVC*DIM + DD};
        L3 bo = {(long)DIM, (long)QKVC + DIM, 2L*QKVC + DIM};
        L3 co = {0, 256L*2*DIM, 2*256L*2*DIM};
        k_mgemm_b3<1,1,2,1><<<dim3(8,48,3), T64, 0, stream>>>(mem_bf, xo, DIM, Ms3,
                                                              inw_bf, wo, DIM, 2*DIM, DIM,
                                                              inb, bo, kvL_bf, co, 2*DIM, 1.f, 0);
    }
    // Gt[l][j][h*M+m] build (depends on Wc + kvL; chain-independent)
    k_gt<2,2,2,1><<<dim3(12,4,24), T256, 0, stream>>>(Wc_bf, kvL_bf, 256L*2*DIM, Gt_bf, 768L*2048, Ms3);
    k_cvt4<<<4096, T256, 0, stream>>>((const float4*)ndw, (ushort4*)ndw_bf2, NEXP*DIM*EDIM/4);

    // ---- quantum attention ----
    k_mgemm<2,2,2,1><<<dim3(32,36), T256, 0, stream>>>(lnx_bf, DIM, NTOK, Wqkv_bf, DIM, QKVC, DIM,
                                                       qkvb, nullptr, 0, nullptr, qkv_bf, QKVC, 1.f, 0);
    k_transv<<<dim3(8,12,NBATCH), T256, 0, stream>>>(qkv_bf, Vt_bf);
    k_mgemm_qk<2,2,2,1><<<dim3(8,8,48), T256, 0, stream>>>(qkv_bf, scores);
    k_supsoft<<<dim3(NTOK), T256, 0, stream>>>(scores, P_bf, wsup, went);
    k_mgemm_pv<1,1,2,1><<<dim3(16,2,48), T64, 0, stream>>>(P_bf, Vt_bf, o_bf);
    k_mgemm<2,2,1,1><<<dim3(64,24), T256, 0, stream>>>(o_bf, DIM, NTOK, Wproj_bf, DIM, DIM, DIM,
                                                       projb, x, DIM, attnd, nullptr, DIM, 1.f, 0);
    // ---- MoE ----
    k_ln<<<NTOK, T256, 0, stream>>>(attnd, ln2g, ln2b, nullptr, lnx_bf);
    k_route<<<NTOK, T256, 0, stream>>>(lnx_bf, Wrout, rb, dr, did, topi, topw, cnt);
    k_prefix<<<1, 1, 0, stream>>>(cnt, prefix);
    k_assign<<<8, T256, 0, stream>>>(topi, prefix, cnt2, rowof, tokof);
    k_gather<<<dim3(PADROWS*96/256), T256, 0, stream>>>(lnx_bf, tokof, Xg_bf);
    k_mgemm_expert_flat<2,2,2,1><<<dim3(PADROWS/64, 48), T256, 0, stream>>>(Xg_bf, DIM, Wexp_bf, DIM, (long)EDIM*DIM,
                                                                            eb, EDIM, prefix, cnt,
                                                                            nullptr, hidden_bf, EDIM, EDIM, DIM, 1);
    k_mgemm_expert_flat<2,2,1,1><<<dim3(PADROWS/32, 24), T256, 0, stream>>>(hidden_bf, EDIM, ndw_bf2, EDIM, (long)DIM*EDIM,
                                                                            ndb, DIM, prefix, cnt,
                                                                            outg, nullptr, DIM, DIM, EDIM, 0);
    k_combine<<<dim3(6144), T256, 0, stream>>>(attnd, outg, rowof, topw, eo, inx_bf);
    // ---- fractal memory (3 levels; K/V + Gt precomputed above; 3 dispatches/level) ----
    int Ms[3] = {64, 128, 256};
    for (int l=0; l<3; ++l){
        const u16* iwl = inw_bf + (size_t)l*QKVC*DIM;
        int M = Ms[l];
        k_mgemm<2,2,1,1><<<dim3(64,24), T256, 0, stream>>>(inx_bf, DIM, NTOK, iwl, DIM, DIM, DIM,
                                                           inb + (size_t)l*QKVC, nullptr, 0, nullptr, qm_bf, DIM, 1.f, 0);
        k_memqk_soft<<<dim3(NTOK/64, MHEADS), T256, 0, stream>>>(qm_bf, kvL_bf + (size_t)l*256*2*DIM, 2*DIM,
                                                                 Pm_bf, M, 0.10206207261596577f);
        // fused PV + (out-proj ∘ proc-proj): a_l = Pcat @ Gt[l]^T + bc ; accum += a_l ; inx_bf = bf16(a_l)
        k_mgemm<2,2,1,1><<<dim3(64,24), T256, 0, stream>>>(Pm_bf, 8*M, NTOK, Gt_bf + (size_t)l*768*2048, 8*M, DIM, 8*M,
                                                           bcb + (size_t)l*DIM, (l==0 ? eo : accum), DIM,
                                                           accum, inx_bf, DIM, 1.f, 0);
    }
    k_ln<<<NTOK, T256, 0, stream>>>(accum, ln3g, ln3b, outf, nullptr);
}